// Round 11
// baseline (3215.332 us; speedup 1.0000x reference)
//
#include <hip/hip_runtime.h>

// StageBlocks: FPS -> ball-query -> conv/BN/max -> 2x InvResMLP on MI355X.
// Discrete decisions (FPS argmax, ball membership) use contract-off f32 to
// match XLA/np rounding bitwise. BN via sufficient statistics.
// R22: R21 + EXACT wave-level FPS pruning. Points are loaded in pg_xyz's
// cell-sorted order (built by a new tiny k_bin_pos first launch), so each
// wave owns a spatial slab. Per iteration a wave computes a bitwise-true
// lower bound lb2 = sq3(clamp(c,bbox)-c) (RNE rounding is monotone ->
// lb2 <= d2 for every point in the bbox) and SKIPS its dist loop +
// reduction when lb2 >= its own previous wave-max ds (then min(ds,d2)=ds
// for all its points -> wave max & min-idx-at-max unchanged -> republish
// previous tournament key). Tie-break preserved exactly: per-lane
// min-ORIGINAL-index at wave max (orig indices from pg_xyz.w, packed
// 2xu16/VGPR), DPP-min reduced; cross-wave u64 tournament is partition-
// independent. Tail/bq byte-identical to R21 (atomic-fixed, proven).

#define BB 4
#define NN 8192
#define MM 2048
#define HM 1024  // FPS split point
#define KK 32
#define CI 64
#define CO 128
#define SG 16    // stat groups
#define CAPH 192 // grid-bq hit cap (expected 34 bq1 / 69 bq2)

typedef float vf2 __attribute__((ext_vector_type(2)));

// stats layout (doubles)
#define ST_X 0
#define MO_PS 256
#define MO_PE 272
#define ST1 288                     // 2 x SG x 256 (block0, block1)
#define ST2A (288 + 2 * SG * 256)   // 2 x SG x 256
#define ST2B (ST2A + 2 * SG * 256)  // 2 x 256
#define ST_TOTAL (ST2B + 512)

__device__ __forceinline__ float sq3(float dx, float dy, float dz) {
#pragma clang fp contract(off)
  return dx * dx + dy * dy + dz * dz;  // ((x+y)+z), no FMA: matches XLA/np
}

__device__ __forceinline__ void fin_stats_d(const double* st, float gam,
                                            float bet, double cnt, int ch,
                                            float* sc, float* sh) {
  double mean = st[ch] / cnt;
  double var = st[128 + ch] / cnt - mean * mean;
  if (var < 0) var = 0;
  double s = (double)gam / sqrt(var + 1e-5);
  *sc = (float)s;
  *sh = (float)((double)bet - mean * s);
}

// grouped (SG partial sums) variant
__device__ __forceinline__ void fin_grp_d(const double* st, float gam,
                                          float bet, double cnt, int ch,
                                          float* sc, float* sh) {
  double sum = 0, ssq = 0;
#pragma unroll
  for (int g = 0; g < SG; g++) {
    sum += st[g * 256 + ch];
    ssq += st[g * 256 + 128 + ch];
  }
  double mean = sum / cnt;
  double var = ssq / cnt - mean * mean;
  if (var < 0) var = 0;
  double s = (double)gam / sqrt(var + 1e-5);
  *sc = (float)s;
  *sh = (float)((double)bet - mean * s);
}

__device__ __forceinline__ void fin_mom_d(const double* mo, const float* Wrow,
                                          float gam, float bet, double cnt,
                                          float* sc, float* sh) {
  double w0 = Wrow[0], w1 = Wrow[1], w2 = Wrow[2];
  double mx = mo[0] / cnt, my = mo[1] / cnt, mz = mo[2] / cnt;
  double sxx = mo[3] / cnt, sxy = mo[4] / cnt, sxz = mo[5] / cnt;
  double syy = mo[6] / cnt, syz = mo[7] / cnt, szz = mo[8] / cnt;
  double mean = w0 * mx + w1 * my + w2 * mz;
  double ey2 = w0 * w0 * sxx + w1 * w1 * syy + w2 * w2 * szz +
               2.0 * (w0 * w1 * sxy + w0 * w2 * sxz + w1 * w2 * syz);
  double var = ey2 - mean * mean;
  if (var < 0) var = 0;
  double s = (double)gam / sqrt(var + 1e-5);
  *sc = (float)s;
  *sh = (float)((double)bet - mean * s);
}

// ---------------- DPP helpers ----------------
template <int CTRL>
__device__ __forceinline__ int dpp_i(int v) {
  return __builtin_amdgcn_update_dpp(v, v, CTRL, 0xF, 0xF, false);
}
template <int CTRL>
__device__ __forceinline__ float dpp_f(float v) {
  return __int_as_float(dpp_i<CTRL>(__float_as_int(v)));
}
// reduce-to-lane63 chains
__device__ __forceinline__ float wave_fmax63(float v) {
  v = fmaxf(v, dpp_f<0x111>(v));
  v = fmaxf(v, dpp_f<0x112>(v));
  v = fmaxf(v, dpp_f<0x114>(v));
  v = fmaxf(v, dpp_f<0x118>(v));
  v = fmaxf(v, dpp_f<0x142>(v));
  v = fmaxf(v, dpp_f<0x143>(v));
  return v;
}
__device__ __forceinline__ float wave_fmin63(float v) {
  v = fminf(v, dpp_f<0x111>(v));
  v = fminf(v, dpp_f<0x112>(v));
  v = fminf(v, dpp_f<0x114>(v));
  v = fminf(v, dpp_f<0x118>(v));
  v = fminf(v, dpp_f<0x142>(v));
  v = fminf(v, dpp_f<0x143>(v));
  return v;
}
__device__ __forceinline__ unsigned wave_umin63(unsigned v) {
  unsigned u;
  u = (unsigned)dpp_i<0x111>((int)v); v = u < v ? u : v;
  u = (unsigned)dpp_i<0x112>((int)v); v = u < v ? u : v;
  u = (unsigned)dpp_i<0x114>((int)v); v = u < v ? u : v;
  u = (unsigned)dpp_i<0x118>((int)v); v = u < v ? u : v;
  u = (unsigned)dpp_i<0x142>((int)v); v = u < v ? u : v;
  u = (unsigned)dpp_i<0x143>((int)v); v = u < v ? u : v;
  return v;
}

#define FT 512
#define NP 8  // float2 pairs per thread = 16 points
#define NW 8

// ---------------- grid-accelerated ball query (one wave per query) -------
__device__ __forceinline__ void bq_grid(
    int pair, const float* __restrict__ pts, int npts,
    const float4* __restrict__ gxyz, const int* __restrict__ gstart, int G,
    float gs, float rad, float rsq, float inv_r, int* __restrict__ sel,
    const float* __restrict__ cent, int lane, int* __restrict__ s_hitw,
    int* __restrict__ s_selw, float* __restrict__ s_momw) {
  const float* C = cent + (size_t)pair * 3;
  float cx = C[0], cy = C[1], cz = C[2];
  unsigned long long ltm = (1ull << lane) - 1ull;
  int x0 = (int)((cx - rad - 1e-5f) * gs); x0 = x0 < 0 ? 0 : x0;
  int x1 = (int)((cx + rad + 1e-5f) * gs); x1 = x1 > G - 1 ? G - 1 : x1;
  int y0 = (int)((cy - rad - 1e-5f) * gs); y0 = y0 < 0 ? 0 : y0;
  int y1 = (int)((cy + rad + 1e-5f) * gs); y1 = y1 > G - 1 ? G - 1 : y1;
  int z0 = (int)((cz - rad - 1e-5f) * gs); z0 = z0 < 0 ? 0 : z0;
  int z1 = (int)((cz + rad + 1e-5f) * gs); z1 = z1 > G - 1 ? G - 1 : z1;
  int cnt = 0;
  for (int zz = z0; zz <= z1; zz++) {
    for (int yy = y0; yy <= y1; yy++) {
      int brow = (zz * G + yy) * G;
      int sbeg = gstart[brow + x0];
      int send = gstart[brow + x1 + 1];  // x-cells contiguous in bin order
      for (int base = sbeg; base < send; base += 64) {
        int j = base + lane;
        bool h = false;
        int pi = 0;
        if (j < send) {
          float4 v = gxyz[j];
          pi = __float_as_int(v.w);
          h = sq3(v.x - cx, v.y - cy, v.z - cz) < rsq;
        }
        unsigned long long mb = __ballot(h);
        if (mb) {
          int k = cnt + __popcll(mb & ltm);
          if (h && k < CAPH) s_hitw[k] = pi;
          cnt += __popcll(mb);
        }
      }
    }
  }
  __syncthreads();  // collect done, s_hit stable (uniform across waves)
  int total;
  if (cnt <= CAPH) {
    // rank-select: KK smallest indices ascending (indices distinct)
    for (int l = lane; l < cnt; l += 64) {
      int v = s_hitw[l];
      int rk = 0;
      for (int j = 0; j < cnt; j++) rk += (s_hitw[j] < v);
      if (rk < KK) s_selw[rk] = v;
    }
    total = cnt < KK ? cnt : KK;
  } else {
    // brute fallback: index-ordered first-KK scan (never expected)
    int bcnt = 0;
    int nit = npts >> 6;
    for (int ch = 0; ch < nit; ch++) {
      int i0 = (ch << 6) + lane;
      float a0 = pts[i0 * 3 + 0], a1 = pts[i0 * 3 + 1], a2 = pts[i0 * 3 + 2];
      bool h = sq3(a0 - cx, a1 - cy, a2 - cz) < rsq;
      unsigned long long mb = __ballot(h);
      if (mb) {
        int k = bcnt + __popcll(mb & ltm);
        if (h && k < KK) s_selw[k] = i0;
        bcnt += __popcll(mb);
      }
      if (bcnt >= KK) break;
    }
    total = bcnt < KK ? bcnt : KK;
  }
  __syncthreads();  // s_sel stable
  int myidx = 0;
  if (lane < KK) {
    int v = (lane < total) ? s_selw[lane] : s_selw[0];
    sel[(size_t)pair * KK + lane] = v;
    myidx = v;
  }
  float gx = 0.f, gy = 0.f, gz = 0.f;
  if (lane < KK) {
    gx = (pts[myidx * 3 + 0] - cx) * inv_r;
    gy = (pts[myidx * 3 + 1] - cy) * inv_r;
    gz = (pts[myidx * 3 + 2] - cz) * inv_r;
  }
  float v9[9] = {gx, gy, gz, gx * gx, gx * gy, gx * gz, gy * gy, gy * gz,
                 gz * gz};
#pragma unroll
  for (int j = 0; j < 9; j++) {
#pragma unroll
    for (int off = 32; off > 0; off >>= 1) v9[j] += __shfl_xor(v9[j], off);
  }
  if (lane == 0) {
#pragma unroll
    for (int j = 0; j < 9; j++) s_momw[j] = v9[j];
  }
}

// ---------------- pos-grid build (10^3 bins, one block per batch) --------
__global__ __launch_bounds__(FT) void k_bin_pos(const float* __restrict__ pos,
                                                int* __restrict__ pg_start,
                                                float4* __restrict__ pg_xyz) {
  __shared__ int cb[1024], rb[1024];
  int t = threadIdx.x, bb = blockIdx.x;
  const float* P = pos + (size_t)bb * NN * 3;
  for (int i = t; i < 1000; i += FT) cb[i] = 0;
  __syncthreads();
  for (int i = t; i < NN; i += FT) {
    float px = P[i * 3 + 0], py = P[i * 3 + 1], pz = P[i * 3 + 2];
    int bx = (int)(px * 10.f); bx = bx > 9 ? 9 : bx;
    int by = (int)(py * 10.f); by = by > 9 ? 9 : by;
    int bz = (int)(pz * 10.f); bz = bz > 9 ? 9 : bz;
    atomicAdd(&cb[(bz * 10 + by) * 10 + bx], 1);
  }
  __syncthreads();
  if (t == 0) {
    int acc = 0;
    for (int j = 0; j < 1000; j++) {
      pg_start[bb * 1024 + j] = acc;
      rb[j] = acc;
      acc += cb[j];
    }
    pg_start[bb * 1024 + 1000] = acc;  // == NN sentinel
  }
  __syncthreads();
  for (int i = t; i < NN; i += FT) {
    float px = P[i * 3 + 0], py = P[i * 3 + 1], pz = P[i * 3 + 2];
    int bx = (int)(px * 10.f); bx = bx > 9 ? 9 : bx;
    int by = (int)(py * 10.f); by = by > 9 ? 9 : by;
    int bz = (int)(pz * 10.f); bz = bz > 9 ? 9 : bz;
    int slot = atomicAdd(&rb[(bz * 10 + by) * 10 + bx], 1);
    float4 v;
    v.x = px; v.y = py; v.z = pz; v.w = __int_as_float(i);
    pg_xyz[(size_t)bb * NN + slot] = v;
  }
}

// ---- FPS stage A (0..HM) with wave pruning + conv_x cotenant ------------
__global__ __launch_bounds__(FT) void k_fps_conv(
    const float* __restrict__ pos, const float* __restrict__ x,
    const float* __restrict__ W_x, float* __restrict__ cent,
    float* __restrict__ fpre, double* __restrict__ stats,
    float* __restrict__ gds, const float4* __restrict__ pg_xyz) {
  __shared__ alignas(16) unsigned long long s_key[2][NW];  // 128 B
  __shared__ alignas(16) float s_pts[NN * 3];   // 96 KB point table (orig)
  __shared__ alignas(16) float s_cent[MM * 3];  // 24 KB centroid staging
  int t = threadIdx.x;
  if (blockIdx.x >= BB) {
    // ---- conv part: 64->128 over BB*NN rows, 256 blocks x 512 threads ----
    int cb2 = blockIdx.x - BB;
    int o = t & 127, q = t >> 7;  // q wave-uniform
    float4 w[CI / 4];
    const float4* Wv = (const float4*)(W_x + (size_t)o * CI);
#pragma unroll
    for (int i = 0; i < CI / 4; i++) w[i] = Wv[i];
    int row0 = cb2 * 128;
    float ssum = 0.f, ssq = 0.f;
    for (int r = 0; r < 128; r += 4) {
      int row = __builtin_amdgcn_readfirstlane(row0 + r + q);
      const float* xr = x + (size_t)row * CI;
      float acc = 0.f;
#pragma unroll
      for (int i = 0; i < CI / 4; i++) {
        float4 a = *(const float4*)(xr + 4 * i);
        acc += a.x * w[i].x + a.y * w[i].y + a.z * w[i].z + a.w * w[i].w;
      }
      fpre[(size_t)row * CO + o] = acc;
      ssum += acc;
      ssq += acc * acc;
    }
    atomicAdd(&stats[ST_X + o], (double)ssum);
    atomicAdd(&stats[ST_X + 128 + o], (double)ssq);
    return;
  }
  // ---- FPS stage A (sorted layout + pruning) ----
  int b = blockIdx.x;
  const float* P = pos + (size_t)b * NN * 3;
  const float4* G = pg_xyz + (size_t)b * NN;
  float* C = cent + (size_t)b * MM * 3;
  int lane = t & 63, w = t >> 6;
  int ws = __builtin_amdgcn_readfirstlane(w);
  for (int i = t; i < (NN * 3) / 4; i += FT) {
    ((float4*)s_pts)[i] = ((const float4*)P)[i];
  }
  vf2 px[NP], py[NP], pz[NP], ds[NP];
  unsigned oid[NP];
#pragma unroll
  for (int s = 0; s < NP; s++) {
    int ia = (2 * s) * FT + t;
    int ib = ia + FT;
    float4 va = G[ia];
    float4 vb = G[ib];
    px[s] = (vf2){va.x, vb.x};
    py[s] = (vf2){va.y, vb.y};
    pz[s] = (vf2){va.z, vb.z};
    oid[s] = ((unsigned)__float_as_int(va.w) & 0xffffu) |
             ((unsigned)__float_as_int(vb.w) << 16);
    ds[s] = (vf2){1e10f, 1e10f};
  }
  // per-wave bbox (exact f32 min/max of the wave's points)
  float mnx = 1e30f, mxx = -1e30f, mny = 1e30f, mxy = -1e30f;
  float mnz = 1e30f, mxz = -1e30f;
#pragma unroll
  for (int s = 0; s < NP; s++) {
    mnx = fminf(mnx, fminf(px[s].x, px[s].y));
    mxx = fmaxf(mxx, fmaxf(px[s].x, px[s].y));
    mny = fminf(mny, fminf(py[s].x, py[s].y));
    mxy = fmaxf(mxy, fmaxf(py[s].x, py[s].y));
    mnz = fminf(mnz, fminf(pz[s].x, pz[s].y));
    mxz = fmaxf(mxz, fmaxf(pz[s].x, pz[s].y));
  }
  float bx0 = __int_as_float(
      __builtin_amdgcn_readlane(__float_as_int(wave_fmin63(mnx)), 63));
  float bx1 = __int_as_float(
      __builtin_amdgcn_readlane(__float_as_int(wave_fmax63(mxx)), 63));
  float by0 = __int_as_float(
      __builtin_amdgcn_readlane(__float_as_int(wave_fmin63(mny)), 63));
  float by1 = __int_as_float(
      __builtin_amdgcn_readlane(__float_as_int(wave_fmax63(mxy)), 63));
  float bz0 = __int_as_float(
      __builtin_amdgcn_readlane(__float_as_int(wave_fmin63(mnz)), 63));
  float bz1 = __int_as_float(
      __builtin_amdgcn_readlane(__float_as_int(wave_fmax63(mxz)), 63));
  float pwmax = 1e30f;  // force processing on first iteration
  unsigned long long pkey = 0;
  float lx = P[0], ly = P[1], lz = P[2];
  if (t == 0) {
    s_cent[0] = lx;
    s_cent[1] = ly;
    s_cent[2] = lz;
  }
  __syncthreads();  // tables ready
  for (int m = 1; m < HM; m++) {
    int pb = m & 1;
    // exact lower bound: clamp(c,bbox); monotone RNE => lb2 <= d2 for all
    // wave points. Skip iff lb2 >= wave's current max ds (then every
    // min(ds,d2)=ds -> wave key unchanged).
    float qx = fminf(fmaxf(lx, bx0), bx1);
    float qy = fminf(fmaxf(ly, by0), by1);
    float qz = fminf(fmaxf(lz, bz0), bz1);
    float lb2 = sq3(qx - lx, qy - ly, qz - lz);
    if (lb2 >= pwmax) {
      if (lane == 0) s_key[pb][ws] = pkey;  // republish unchanged key
    } else {
      vf2 l2x = (vf2){lx, lx}, l2y = (vf2){ly, ly}, l2z = (vf2){lz, lz};
      vf2 bmax = (vf2){-1.0f, -1.0f};
      {
#pragma clang fp contract(off)
#pragma unroll
        for (int s = 0; s < NP; s++) {
          vf2 dx = px[s] - l2x;
          vf2 dy = py[s] - l2y;
          vf2 dz = pz[s] - l2z;
          vf2 d2 = dx * dx + dy * dy + dz * dz;  // per-lane IEEE, no FMA
          vf2 nd = __builtin_elementwise_min(ds[s], d2);
          ds[s] = nd;
          bmax = __builtin_elementwise_max(bmax, nd);
        }
      }
      float bv = wave_fmax63(fmaxf(bmax.x, bmax.y));
      float wmax =
          __int_as_float(__builtin_amdgcn_readlane(__float_as_int(bv), 63));
      // per-lane min ORIGINAL index among points at wave max
      unsigned mi = 0xffffffffu;
#pragma unroll
      for (int s = 0; s < NP; s++) {
        if (ds[s].x == wmax) {
          unsigned a = oid[s] & 0xffffu;
          mi = a < mi ? a : mi;
        }
        if (ds[s].y == wmax) {
          unsigned a = oid[s] >> 16;
          mi = a < mi ? a : mi;
        }
      }
      mi = wave_umin63(mi);
      unsigned miw = (unsigned)__builtin_amdgcn_readlane((int)mi, 63);
      pwmax = wmax;
      pkey = ((unsigned long long)__float_as_uint(wmax) << 32) |
             (unsigned long long)(~miw);
      if (lane == 0) s_key[pb][ws] = pkey;
    }
    __syncthreads();  // single barrier per iteration
    const ulonglong2* kp = (const ulonglong2*)(&s_key[pb][0]);
    ulonglong2 q0 = kp[0];
    ulonglong2 q1 = kp[1];
    ulonglong2 q2 = kp[2];
    ulonglong2 q3 = kp[3];
    unsigned long long a0 = q0.x > q0.y ? q0.x : q0.y;
    unsigned long long a1 = q1.x > q1.y ? q1.x : q1.y;
    unsigned long long a2 = q2.x > q2.y ? q2.x : q2.y;
    unsigned long long a3 = q3.x > q3.y ? q3.x : q3.y;
    a0 = a0 > a1 ? a0 : a1;
    a2 = a2 > a3 ? a2 : a3;
    unsigned long long kw = a0 > a2 ? a0 : a2;
    unsigned gidx = ~(unsigned)(kw & 0xffffffffull);
    lx = s_pts[gidx * 3 + 0];
    ly = s_pts[gidx * 3 + 1];
    lz = s_pts[gidx * 3 + 2];
    if (t == 0) {
      s_cent[m * 3 + 0] = lx;
      s_cent[m * 3 + 1] = ly;
      s_cent[m * 3 + 2] = lz;
    }
  }
  __syncthreads();
  // dump centroids 0..HM-1 and ds state (bit-exact carry, SLOT order)
  for (int i = t; i < (HM * 3) / 4; i += FT) {
    ((float4*)C)[i] = ((const float4*)s_cent)[i];
  }
  float2* gd = (float2*)gds + (size_t)b * NP * FT;
#pragma unroll
  for (int s = 0; s < NP; s++) {
    float2 v;
    v.x = ds[s].x;
    v.y = ds[s].y;
    gd[s * FT + t] = v;
  }
}

// ---------------- FPS stage B (HM..MM, pruned) + grid-bq1a cotenant ------
__global__ __launch_bounds__(FT) void k_fps_bq(
    const float* __restrict__ pos, float* __restrict__ cent,
    const float* __restrict__ gds, int* __restrict__ sel1,
    double* __restrict__ stats, const int* __restrict__ pg_start,
    const float4* __restrict__ pg_xyz) {
  __shared__ alignas(16) unsigned long long s_key[2][NW];
  __shared__ alignas(16) float s_pts[NN * 3];   // 96 KB
  __shared__ alignas(16) float s_cent[MM * 3];  // 24 KB
  __shared__ int s_hit[NW][CAPH];               // 6 KB
  __shared__ int s_sel[NW][KK];
  __shared__ float s_mom[NW][9];
  int t = threadIdx.x;
  int lane = t & 63, w = t >> 6;
  if (blockIdx.x >= BB) {
    // ---- grid-bq1 for first-half centroids (m < HM): 8 pairs/block ----
    int pi = (blockIdx.x - BB) * 8 + w;  // 0..4095
    int bb = pi >> 10, mi = pi & (HM - 1);
    int pair = bb * MM + mi;
    bq_grid(pair, pos + (size_t)bb * NN * 3, NN, pg_xyz + (size_t)bb * NN,
            pg_start + bb * 1024, 10, 10.f, 0.1f, 0.01f, 10.f, sel1, cent,
            lane, s_hit[w], s_sel[w], s_mom[w]);
    __syncthreads();
    if (t < 9) {
      double a = (double)s_mom[0][t];
#pragma unroll
      for (int j = 1; j < NW; j++) a += s_mom[j][t];
      atomicAdd(&stats[MO_PS + t], a);
    }
    return;
  }
  // ---- FPS resume (sorted layout + pruning) ----
  int b = blockIdx.x;
  const float* P = pos + (size_t)b * NN * 3;
  const float4* G = pg_xyz + (size_t)b * NN;
  float* C = cent + (size_t)b * MM * 3;
  int ws = __builtin_amdgcn_readfirstlane(w);
  for (int i = t; i < (NN * 3) / 4; i += FT) {
    ((float4*)s_pts)[i] = ((const float4*)P)[i];
  }
  vf2 px[NP], py[NP], pz[NP], ds[NP];
  unsigned oid[NP];
  const float2* gd = (const float2*)gds + (size_t)b * NP * FT;
#pragma unroll
  for (int s = 0; s < NP; s++) {
    int ia = (2 * s) * FT + t;
    int ib = ia + FT;
    float4 va = G[ia];
    float4 vb = G[ib];
    px[s] = (vf2){va.x, vb.x};
    py[s] = (vf2){va.y, vb.y};
    pz[s] = (vf2){va.z, vb.z};
    oid[s] = ((unsigned)__float_as_int(va.w) & 0xffffu) |
             ((unsigned)__float_as_int(vb.w) << 16);
    float2 v = gd[s * FT + t];
    ds[s] = (vf2){v.x, v.y};
  }
  float mnx = 1e30f, mxx = -1e30f, mny = 1e30f, mxy = -1e30f;
  float mnz = 1e30f, mxz = -1e30f;
#pragma unroll
  for (int s = 0; s < NP; s++) {
    mnx = fminf(mnx, fminf(px[s].x, px[s].y));
    mxx = fmaxf(mxx, fmaxf(px[s].x, px[s].y));
    mny = fminf(mny, fminf(py[s].x, py[s].y));
    mxy = fmaxf(mxy, fmaxf(py[s].x, py[s].y));
    mnz = fminf(mnz, fminf(pz[s].x, pz[s].y));
    mxz = fmaxf(mxz, fmaxf(pz[s].x, pz[s].y));
  }
  float bx0 = __int_as_float(
      __builtin_amdgcn_readlane(__float_as_int(wave_fmin63(mnx)), 63));
  float bx1 = __int_as_float(
      __builtin_amdgcn_readlane(__float_as_int(wave_fmax63(mxx)), 63));
  float by0 = __int_as_float(
      __builtin_amdgcn_readlane(__float_as_int(wave_fmin63(mny)), 63));
  float by1 = __int_as_float(
      __builtin_amdgcn_readlane(__float_as_int(wave_fmax63(mxy)), 63));
  float bz0 = __int_as_float(
      __builtin_amdgcn_readlane(__float_as_int(wave_fmin63(mnz)), 63));
  float bz1 = __int_as_float(
      __builtin_amdgcn_readlane(__float_as_int(wave_fmax63(mxz)), 63));
  float pwmax = 1e30f;
  unsigned long long pkey = 0;
  float lx = C[(HM - 1) * 3 + 0];
  float ly = C[(HM - 1) * 3 + 1];
  float lz = C[(HM - 1) * 3 + 2];
  __syncthreads();  // tables ready
  for (int m = HM; m < MM; m++) {
    int pb = m & 1;
    float qx = fminf(fmaxf(lx, bx0), bx1);
    float qy = fminf(fmaxf(ly, by0), by1);
    float qz = fminf(fmaxf(lz, bz0), bz1);
    float lb2 = sq3(qx - lx, qy - ly, qz - lz);
    if (lb2 >= pwmax) {
      if (lane == 0) s_key[pb][ws] = pkey;
    } else {
      vf2 l2x = (vf2){lx, lx}, l2y = (vf2){ly, ly}, l2z = (vf2){lz, lz};
      vf2 bmax = (vf2){-1.0f, -1.0f};
      {
#pragma clang fp contract(off)
#pragma unroll
        for (int s = 0; s < NP; s++) {
          vf2 dx = px[s] - l2x;
          vf2 dy = py[s] - l2y;
          vf2 dz = pz[s] - l2z;
          vf2 d2 = dx * dx + dy * dy + dz * dz;  // per-lane IEEE, no FMA
          vf2 nd = __builtin_elementwise_min(ds[s], d2);
          ds[s] = nd;
          bmax = __builtin_elementwise_max(bmax, nd);
        }
      }
      float bv = wave_fmax63(fmaxf(bmax.x, bmax.y));
      float wmax =
          __int_as_float(__builtin_amdgcn_readlane(__float_as_int(bv), 63));
      unsigned mi = 0xffffffffu;
#pragma unroll
      for (int s = 0; s < NP; s++) {
        if (ds[s].x == wmax) {
          unsigned a = oid[s] & 0xffffu;
          mi = a < mi ? a : mi;
        }
        if (ds[s].y == wmax) {
          unsigned a = oid[s] >> 16;
          mi = a < mi ? a : mi;
        }
      }
      mi = wave_umin63(mi);
      unsigned miw = (unsigned)__builtin_amdgcn_readlane((int)mi, 63);
      pwmax = wmax;
      pkey = ((unsigned long long)__float_as_uint(wmax) << 32) |
             (unsigned long long)(~miw);
      if (lane == 0) s_key[pb][ws] = pkey;
    }
    __syncthreads();
    const ulonglong2* kp = (const ulonglong2*)(&s_key[pb][0]);
    ulonglong2 q0 = kp[0];
    ulonglong2 q1 = kp[1];
    ulonglong2 q2 = kp[2];
    ulonglong2 q3 = kp[3];
    unsigned long long a0 = q0.x > q0.y ? q0.x : q0.y;
    unsigned long long a1 = q1.x > q1.y ? q1.x : q1.y;
    unsigned long long a2 = q2.x > q2.y ? q2.x : q2.y;
    unsigned long long a3 = q3.x > q3.y ? q3.x : q3.y;
    a0 = a0 > a1 ? a0 : a1;
    a2 = a2 > a3 ? a2 : a3;
    unsigned long long kw = a0 > a2 ? a0 : a2;
    unsigned gidx = ~(unsigned)(kw & 0xffffffffull);
    lx = s_pts[gidx * 3 + 0];
    ly = s_pts[gidx * 3 + 1];
    lz = s_pts[gidx * 3 + 2];
    if (t == 0) {
      s_cent[m * 3 + 0] = lx;
      s_cent[m * 3 + 1] = ly;
      s_cent[m * 3 + 2] = lz;
    }
  }
  __syncthreads();
  for (int i = t + (HM * 3) / 4; i < (MM * 3) / 4; i += FT) {
    ((float4*)C)[i] = ((const float4*)s_cent)[i];
  }
}

// ---------------- cent-grid build (5^3 bins, one block per batch) --------
__global__ __launch_bounds__(256) void k_bin_cent(const float* __restrict__ cent,
                                                  int* __restrict__ cg_start,
                                                  float4* __restrict__ cg_xyz) {
  __shared__ int cb[128], rb[128];
  int t = threadIdx.x, bb = blockIdx.x;
  const float* C = cent + (size_t)bb * MM * 3;
  for (int i = t; i < 125; i += 256) cb[i] = 0;
  __syncthreads();
  for (int i = t; i < MM; i += 256) {
    float px = C[i * 3 + 0], py = C[i * 3 + 1], pz = C[i * 3 + 2];
    int bx = (int)(px * 5.f); bx = bx > 4 ? 4 : bx;
    int by = (int)(py * 5.f); by = by > 4 ? 4 : by;
    int bz = (int)(pz * 5.f); bz = bz > 4 ? 4 : bz;
    atomicAdd(&cb[(bz * 5 + by) * 5 + bx], 1);
  }
  __syncthreads();
  if (t == 0) {
    int acc = 0;
    for (int j = 0; j < 125; j++) {
      cg_start[bb * 128 + j] = acc;
      rb[j] = acc;
      acc += cb[j];
    }
    cg_start[bb * 128 + 125] = acc;  // == MM sentinel
  }
  __syncthreads();
  for (int i = t; i < MM; i += 256) {
    float px = C[i * 3 + 0], py = C[i * 3 + 1], pz = C[i * 3 + 2];
    int bx = (int)(px * 5.f); bx = bx > 4 ? 4 : bx;
    int by = (int)(py * 5.f); by = by > 4 ? 4 : by;
    int bz = (int)(pz * 5.f); bz = bz > 4 ? 4 : bz;
    int slot = atomicAdd(&rb[(bz * 5 + by) * 5 + bx], 1);
    float4 v;
    v.x = px; v.y = py; v.z = pz; v.w = __int_as_float(i);
    cg_xyz[(size_t)bb * MM + slot] = v;
  }
}

// ---------------- grid-bq: visible bq1 [HM,MM) + bq2 (all) ---------------
__global__ __launch_bounds__(256) void k_bq_rest(
    const float* __restrict__ pos, const float* __restrict__ cent,
    const int* __restrict__ pg_start, const float4* __restrict__ pg_xyz,
    const int* __restrict__ cg_start, const float4* __restrict__ cg_xyz,
    int* __restrict__ sel1, int* __restrict__ sel2,
    double* __restrict__ stats) {
  __shared__ int s_hit[4][CAPH];
  __shared__ int s_sel[4][KK];
  __shared__ float s_mom[4][9];
  int t = threadIdx.x, lane = t & 63, w = t >> 6;
  int mo;
  if (blockIdx.x < (BB * (MM - HM)) / 4) {  // 1024 blocks: bq1 m >= HM
    int pi = blockIdx.x * 4 + w;            // 0..4095
    int bb = pi >> 10;                      // MM-HM == 1024
    int mi = (pi & (HM - 1)) + HM;
    int pair = bb * MM + mi;
    bq_grid(pair, pos + (size_t)bb * NN * 3, NN, pg_xyz + (size_t)bb * NN,
            pg_start + bb * 1024, 10, 10.f, 0.1f, 0.01f, 10.f, sel1, cent,
            lane, s_hit[w], s_sel[w], s_mom[w]);
    mo = MO_PS;
  } else {  // 2048 blocks: bq2, all pairs
    int pi = (blockIdx.x - (BB * (MM - HM)) / 4) * 4 + w;  // 0..8191
    int bb = pi >> 11;
    bq_grid(pi, cent + (size_t)bb * MM * 3, MM, cg_xyz + (size_t)bb * MM,
            cg_start + bb * 128, 5, 5.f, 0.2f, 0.04f, 5.f, sel2, cent, lane,
            s_hit[w], s_sel[w], s_mom[w]);
    mo = MO_PE;
  }
  __syncthreads();
  if (t < 9) {
    double a = (double)s_mom[0][t] + s_mom[1][t] + s_mom[2][t] + s_mom[3][t];
    atomicAdd(&stats[mo + t], a);
  }
}

// ------ fused stage-1 aggregation + conv1(block0): 32 pairs/block --------
__global__ __launch_bounds__(512) void k_xf_conv1(
    const float* __restrict__ pos, const float* __restrict__ cent,
    const int* __restrict__ sel1, const float* __restrict__ fpre,
    const float* __restrict__ Wps, const float* __restrict__ g_ps,
    const float* __restrict__ b_ps, const float* __restrict__ g_x,
    const float* __restrict__ b_x, const double* __restrict__ stats,
    const float* __restrict__ W1, float* __restrict__ y1a,
    double* __restrict__ st1out) {
  __shared__ alignas(16) float s_sx[128], s_hx[128], s_sp[128], s_hp[128];
  __shared__ alignas(16) float s_w0[128], s_w1[128], s_w2[128];
  __shared__ alignas(16) int s_idx[4][KK];
  __shared__ alignas(16) float s_xf[4][128];
  __shared__ alignas(16) double s_rs[4][128], s_rq[4][128];
  int t = threadIdx.x, bid = blockIdx.x;
  if (t < 128) {
    float sx, hx, sp, hp;
    fin_stats_d(stats + ST_X, g_x[t], b_x[t], (double)(BB * NN), t, &sx, &hx);
    fin_mom_d(stats + MO_PS, Wps + t * 3, g_ps[t], b_ps[t],
              (double)(BB * MM * KK), &sp, &hp);
    s_sx[t] = sx;
    s_hx[t] = hx;
    s_sp[t] = sp;
    s_hp[t] = hp;
    s_w0[t] = Wps[t * 3 + 0];
    s_w1[t] = Wps[t * 3 + 1];
    s_w2[t] = Wps[t * 3 + 2];
  }
  __syncthreads();
  int o = t & 127, sub = t >> 7;  // sub 0..3, wave-uniform
  float sx = s_sx[o], hx = s_hx[o], sp = s_sp[o], hp = s_hp[o];
  float w0 = s_w0[o], w1 = s_w1[o], w2 = s_w2[o];
  double rsum = 0.0, rsq = 0.0;
  for (int p = 0; p < 8; p++) {
    int pair = bid * 32 + p * 4 + sub;
    int b = pair >> 11;
    const float* C = cent + (size_t)pair * 3;
    float cx = C[0], cy = C[1], cz = C[2];
    const float* P = pos + (size_t)b * NN * 3;
    const float* F = fpre + (size_t)b * NN * CO;
    if (o < KK) s_idx[sub][o] = sel1[(size_t)pair * KK + o];
    __syncthreads();
    float acc = -1e30f;
#pragma unroll 4
    for (int k = 0; k < KK; k++) {
      int idx = __builtin_amdgcn_readfirstlane(s_idx[sub][k]);
      float gx = (P[idx * 3 + 0] - cx) * 10.0f;
      float gy = (P[idx * 3 + 1] - cy) * 10.0f;
      float gz = (P[idx * 3 + 2] - cz) * 10.0f;
      float y = fmaxf((w0 * gx + w1 * gy + w2 * gz) * sp + hp, 0.f);
      float f = fmaxf(F[(size_t)idx * CO + o] * sx + hx, 0.f);
      float v = y + f;
      acc = v > acc ? v : acc;
    }
    s_xf[sub][o] = acc;
    __syncthreads();
    const float4* Wv = (const float4*)(W1 + (size_t)o * CO);
    const float4* gv = (const float4*)(&s_xf[sub][0]);
    float dot = 0.f;
#pragma unroll
    for (int i = 0; i < CO / 4; i++) {
      float4 a = gv[i];
      float4 ww = Wv[i];
      dot += a.x * ww.x + a.y * ww.y + a.z * ww.z + a.w * ww.w;
    }
    y1a[(size_t)pair * CO + o] = dot;
    rsum += (double)dot;
    rsq += (double)(dot * dot);
  }
  s_rs[sub][o] = rsum;
  s_rq[sub][o] = rsq;
  __syncthreads();
  int grp = bid & (SG - 1);
  if (t < 128) {
    double a = s_rs[0][t] + s_rs[1][t] + s_rs[2][t] + s_rs[3][t];
    atomicAdd(&st1out[grp * 256 + t], a);
  } else if (t < 256) {
    int c = t - 128;
    double a = s_rq[0][c] + s_rq[1][c] + s_rq[2][c] + s_rq[3][c];
    atomicAdd(&st1out[grp * 256 + 128 + c], a);
  }
}

// ---------------- conv with relu(bn(in)) input, scales from grouped stats -
__global__ __launch_bounds__(256) void k_conv_bnin(
    const float* __restrict__ in, const float* __restrict__ W,
    const double* __restrict__ st_grp, const float* __restrict__ gam,
    const float* __restrict__ bet, float* __restrict__ out,
    double* __restrict__ stats, int rows_per_block) {
  __shared__ float s_sc[128], s_sh[128];
  int t = threadIdx.x;
  if (t < 128) {
    fin_grp_d(st_grp, gam[t], bet[t], (double)(BB * MM), t, &s_sc[t],
              &s_sh[t]);
  }
  __syncthreads();
  int o = t & 127, half = t >> 7;
  float4 w[CO / 4];
  const float4* Wv = (const float4*)(W + (size_t)o * CO);
#pragma unroll
  for (int i = 0; i < CO / 4; i++) w[i] = Wv[i];
  int row0 = blockIdx.x * rows_per_block;
  float ssum = 0.f, ssq = 0.f;
  for (int r = 0; r < rows_per_block; r += 2) {
    int row = __builtin_amdgcn_readfirstlane(row0 + r + half);
    const float* xr = in + (size_t)row * CO;
    float acc = 0.f;
#pragma unroll
    for (int i = 0; i < CO / 4; i++) {
      float4 a = *(const float4*)(xr + 4 * i);
      a.x = fmaxf(a.x * s_sc[4 * i + 0] + s_sh[4 * i + 0], 0.f);
      a.y = fmaxf(a.y * s_sc[4 * i + 1] + s_sh[4 * i + 1], 0.f);
      a.z = fmaxf(a.z * s_sc[4 * i + 2] + s_sh[4 * i + 2], 0.f);
      a.w = fmaxf(a.w * s_sc[4 * i + 3] + s_sh[4 * i + 3], 0.f);
      acc += a.x * w[i].x + a.y * w[i].y + a.z * w[i].z + a.w * w[i].w;
    }
    out[(size_t)row * CO + o] = acc;
    ssum += acc;
    ssq += acc * acc;
  }
  atomicAdd(&stats[o], (double)ssum);
  atomicAdd(&stats[128 + o], (double)ssq);
}

// ---------------- conv1 of block 1 with resid-of-block-0 fused input -----
__global__ __launch_bounds__(256) void k_conv_resid(
    const float* __restrict__ y1prev, const float* __restrict__ y2bprev,
    const double* __restrict__ st1p, const float* __restrict__ g1p,
    const float* __restrict__ b1p, const double* __restrict__ st2bp,
    const float* __restrict__ g2bp, const float* __restrict__ b2bp,
    const float* __restrict__ W, float* __restrict__ y1out,
    double* __restrict__ stats, int rows_per_block) {
  __shared__ float s_s1[128], s_h1[128], s_s2[128], s_h2[128];
  int t = threadIdx.x;
  if (t < 128) {
    fin_grp_d(st1p, g1p[t], b1p[t], (double)(BB * MM), t, &s_s1[t], &s_h1[t]);
    fin_stats_d(st2bp, g2bp[t], b2bp[t], (double)(BB * MM), t, &s_s2[t],
                &s_h2[t]);
  }
  __syncthreads();
  int o = t & 127, half = t >> 7;
  float4 w[CO / 4];
  const float4* Wv = (const float4*)(W + (size_t)o * CO);
#pragma unroll
  for (int i = 0; i < CO / 4; i++) w[i] = Wv[i];
  int row0 = blockIdx.x * rows_per_block;
  float ssum = 0.f, ssq = 0.f;
  for (int r = 0; r < rows_per_block; r += 2) {
    int row = __builtin_amdgcn_readfirstlane(row0 + r + half);
    const float* ar = y1prev + (size_t)row * CO;
    const float* br = y2bprev + (size_t)row * CO;
    float acc = 0.f;
#pragma unroll
    for (int i = 0; i < CO / 4; i++) {
      float4 a = *(const float4*)(ar + 4 * i);
      float4 bb = *(const float4*)(br + 4 * i);
      float x0 = fmaxf(fmaxf(a.x * s_s1[4 * i + 0] + s_h1[4 * i + 0], 0.f) +
                           (bb.x * s_s2[4 * i + 0] + s_h2[4 * i + 0]), 0.f);
      float x1 = fmaxf(fmaxf(a.y * s_s1[4 * i + 1] + s_h1[4 * i + 1], 0.f) +
                           (bb.y * s_s2[4 * i + 1] + s_h2[4 * i + 1]), 0.f);
      float x2 = fmaxf(fmaxf(a.z * s_s1[4 * i + 2] + s_h1[4 * i + 2], 0.f) +
                           (bb.z * s_s2[4 * i + 2] + s_h2[4 * i + 2]), 0.f);
      float x3 = fmaxf(fmaxf(a.w * s_s1[4 * i + 3] + s_h1[4 * i + 3], 0.f) +
                           (bb.w * s_s2[4 * i + 3] + s_h2[4 * i + 3]), 0.f);
      acc += x0 * w[i].x + x1 * w[i].y + x2 * w[i].z + x3 * w[i].w;
    }
    y1out[(size_t)row * CO + o] = acc;
    ssum += acc;
    ssq += acc * acc;
  }
  int grp = blockIdx.x & (SG - 1);
  atomicAdd(&stats[grp * 256 + o], (double)ssum);
  atomicAdd(&stats[grp * 256 + 128 + o], (double)ssq);
}

// ------ fused: g = max_k(relu(bn1(y1[sel2])) + pe); y2a = W2a*g ----------
__global__ __launch_bounds__(512) void k_gconv(
    const float* __restrict__ cent, const int* __restrict__ sel2,
    const float* __restrict__ y1in, const double* __restrict__ st1,
    const float* __restrict__ g1v, const float* __restrict__ b1v,
    const double* __restrict__ mo_pe, const float* __restrict__ Wpe,
    const float* __restrict__ gpe, const float* __restrict__ bpe,
    const float* __restrict__ W2a, float* __restrict__ y2a,
    double* __restrict__ st2a) {
  __shared__ alignas(16) float s_s1[128], s_h1[128], s_se[128], s_he[128];
  __shared__ alignas(16) float s_w0[128], s_w1[128], s_w2[128];
  __shared__ alignas(16) int s_idx[4][KK];
  __shared__ alignas(16) float s_g[4][128];
  __shared__ alignas(16) double s_rs[4][128], s_rq[4][128];
  int t = threadIdx.x, bid = blockIdx.x;
  if (t < 128) {
    float s1, h1, se, he;
    fin_grp_d(st1, g1v[t], b1v[t], (double)(BB * MM), t, &s1, &h1);
    fin_mom_d(mo_pe, Wpe + t * 3, gpe[t], bpe[t], (double)(BB * MM * KK), &se,
              &he);
    s_s1[t] = s1;
    s_h1[t] = h1;
    s_se[t] = se;
    s_he[t] = he;
    s_w0[t] = Wpe[t * 3 + 0];
    s_w1[t] = Wpe[t * 3 + 1];
    s_w2[t] = Wpe[t * 3 + 2];
  }
  __syncthreads();
  int o = t & 127, sub = t >> 7;  // sub 0..3, wave-uniform
  float s1 = s_s1[o], h1 = s_h1[o], se = s_se[o], he = s_he[o];
  float w0 = s_w0[o], w1 = s_w1[o], w2 = s_w2[o];
  double rsum = 0.0, rsq = 0.0;
  for (int p = 0; p < 8; p++) {
    int pair = bid * 32 + p * 4 + sub;
    int b = pair >> 11;
    const float* C = cent + (size_t)pair * 3;
    float cx = C[0], cy = C[1], cz = C[2];
    const float* CB = cent + (size_t)b * MM * 3;
    const float* Y = y1in + (size_t)b * MM * CO;
    if (o < KK) s_idx[sub][o] = sel2[(size_t)pair * KK + o];
    __syncthreads();
    float acc = -1e30f;
#pragma unroll 4
    for (int k = 0; k < KK; k++) {
      int idx = __builtin_amdgcn_readfirstlane(s_idx[sub][k]);
      float gx = (CB[idx * 3 + 0] - cx) * 5.0f;
      float gy = (CB[idx * 3 + 1] - cy) * 5.0f;
      float gz = (CB[idx * 3 + 2] - cz) * 5.0f;
      float pe = fmaxf((w0 * gx + w1 * gy + w2 * gz) * se + he, 0.f);
      float f = fmaxf(Y[(size_t)idx * CO + o] * s1 + h1, 0.f);
      float v = pe + f;
      acc = v > acc ? v : acc;
    }
    s_g[sub][o] = acc;
    __syncthreads();
    const float4* Wv = (const float4*)(W2a + (size_t)o * CO);
    const float4* gv = (const float4*)(&s_g[sub][0]);
    float dot = 0.f;
#pragma unroll
    for (int i = 0; i < CO / 4; i++) {
      float4 a = gv[i];
      float4 ww = Wv[i];
      dot += a.x * ww.x + a.y * ww.y + a.z * ww.z + a.w * ww.w;
    }
    y2a[(size_t)pair * CO + o] = dot;
    rsum += (double)dot;
    rsq += (double)(dot * dot);
  }
  s_rs[sub][o] = rsum;
  s_rq[sub][o] = rsq;
  __syncthreads();
  int grp = bid & (SG - 1);
  if (t < 128) {
    double a = s_rs[0][t] + s_rs[1][t] + s_rs[2][t] + s_rs[3][t];
    atomicAdd(&st2a[grp * 256 + t], a);
  } else if (t < 256) {
    int c = t - 128;
    double a = s_rq[0][c] + s_rq[1][c] + s_rq[2][c] + s_rq[3][c];
    atomicAdd(&st2a[grp * 256 + 128 + c], a);
  }
}

// ---------------- final residual (fin folded per-thread) ----------------
__global__ __launch_bounds__(256) void k_resid_fin(
    const float* __restrict__ y1b, const double* __restrict__ st1,
    const float* __restrict__ g1v, const float* __restrict__ b1v,
    const float* __restrict__ y2b, const double* __restrict__ st2b,
    const float* __restrict__ g2bv, const float* __restrict__ b2bv,
    float* __restrict__ xf) {
  int i = blockIdx.x * 256 + threadIdx.x;
  int o = i & 127;
  float s1, h1, s2, h2;
  fin_grp_d(st1, g1v[o], b1v[o], (double)(BB * MM), o, &s1, &h1);
  fin_stats_d(st2b, g2bv[o], b2bv[o], (double)(BB * MM), o, &s2, &h2);
  float f = fmaxf(y1b[i] * s1 + h1, 0.f);
  float v = y2b[i] * s2 + h2;
  xf[i] = fmaxf(f + v, 0.f);
}

extern "C" void kernel_launch(void* const* d_in, const int* in_sizes, int n_in,
                              void* d_out, int out_size, void* d_ws,
                              size_t ws_size, hipStream_t stream) {
  const float* pos = (const float*)d_in[0];
  const float* x = (const float*)d_in[1];
  const float* W_x = (const float*)d_in[2];
  const float* g_x = (const float*)d_in[3];
  const float* b_x = (const float*)d_in[4];
  const float* W_ps = (const float*)d_in[5];
  const float* g_ps = (const float*)d_in[6];
  const float* b_ps = (const float*)d_in[7];
  const float* W_pe = (const float*)d_in[8];
  const float* g_pe = (const float*)d_in[9];
  const float* b_pe = (const float*)d_in[10];
  const float* W1 = (const float*)d_in[11];
  const float* g1 = (const float*)d_in[12];
  const float* b1 = (const float*)d_in[13];
  const float* W2a = (const float*)d_in[14];
  const float* g2a = (const float*)d_in[15];
  const float* b2a = (const float*)d_in[16];
  const float* W2b = (const float*)d_in[17];
  const float* g2b = (const float*)d_in[18];
  const float* b2b = (const float*)d_in[19];

  float* cent = (float*)d_out;             // (B,M,3)
  float* xf = cent + (size_t)BB * MM * 3;  // (B,M,128)

  char* p = (char*)d_ws;
  double* stats = (double*)p; p += (size_t)ST_TOTAL * sizeof(double);
  int* sel1 = (int*)p;        p += (size_t)BB * MM * KK * sizeof(int);
  int* sel2 = (int*)p;        p += (size_t)BB * MM * KK * sizeof(int);
  float* fpre = (float*)p;    p += (size_t)BB * NN * CO * sizeof(float);
  float* y1a = (float*)p;     p += (size_t)BB * MM * CO * sizeof(float);
  float* y1b = (float*)p;     p += (size_t)BB * MM * CO * sizeof(float);
  float* y2a = (float*)p;     p += (size_t)BB * MM * CO * sizeof(float);
  float* y2b = (float*)p;     p += (size_t)BB * MM * CO * sizeof(float);
  float* gds = (float*)p;     p += (size_t)BB * NP * FT * 2 * sizeof(float);
  float4* pg_xyz = (float4*)p; p += (size_t)BB * NN * sizeof(float4);
  float4* cg_xyz = (float4*)p; p += (size_t)BB * MM * sizeof(float4);
  int* pg_start = (int*)p;    p += (size_t)BB * 1024 * sizeof(int);
  int* cg_start = (int*)p;    p += (size_t)BB * 128 * sizeof(int);

  hipMemsetAsync(stats, 0, (size_t)ST_TOTAL * sizeof(double), stream);
  k_bin_pos<<<BB, FT, 0, stream>>>(pos, pg_start, pg_xyz);
  k_fps_conv<<<BB + 256, FT, 0, stream>>>(pos, x, W_x, cent, fpre, stats, gds,
                                          pg_xyz);
  k_fps_bq<<<BB + (BB * HM) / 8, FT, 0, stream>>>(pos, cent, gds, sel1, stats,
                                                  pg_start, pg_xyz);
  k_bin_cent<<<BB, 256, 0, stream>>>(cent, cg_start, cg_xyz);
  k_bq_rest<<<(BB * (MM - HM)) / 4 + (BB * MM) / 4, 256, 0, stream>>>(
      pos, cent, pg_start, pg_xyz, cg_start, cg_xyz, sel1, sel2, stats);
  k_xf_conv1<<<256, 512, 0, stream>>>(pos, cent, sel1, fpre, W_ps, g_ps,
                                      b_ps, g_x, b_x, stats, W1, y1a,
                                      stats + ST1);
  // ---- InvResMLP block 0 ----
  k_gconv<<<256, 512, 0, stream>>>(cent, sel2, y1a, stats + ST1, g1, b1,
                                   stats + MO_PE, W_pe, g_pe, b_pe, W2a, y2a,
                                   stats + ST2A);
  k_conv_bnin<<<128, 256, 0, stream>>>(y2a, W2b, stats + ST2A, g2a, b2a, y2b,
                                       stats + ST2B, 64);
  // ---- InvResMLP block 1 (resid of block 0 fused into conv1) ----
  k_conv_resid<<<128, 256, 0, stream>>>(
      y1a, y2b, stats + ST1, g1, b1, stats + ST2B, g2b, b2b, W1 + CO * CO, y1b,
      stats + ST1 + SG * 256, 64);
  k_gconv<<<256, 512, 0, stream>>>(cent, sel2, y1b, stats + ST1 + SG * 256,
                                   g1 + 128, b1 + 128, stats + MO_PE, W_pe,
                                   g_pe, b_pe, W2a + CO * CO, y2a,
                                   stats + ST2A + SG * 256);
  k_conv_bnin<<<128, 256, 0, stream>>>(y2a, W2b + CO * CO,
                                       stats + ST2A + SG * 256, g2a + 128,
                                       b2a + 128, y2b, stats + ST2B + 256, 64);
  k_resid_fin<<<(BB * MM * CO) / 256, 256, 0, stream>>>(
      y1b, stats + ST1 + SG * 256, g1 + 128, b1 + 128, y2b,
      stats + ST2B + 256, g2b + 128, b2b + 128, xf);
}

// Round 12
// 2462.589 us; speedup vs baseline: 1.3057x; 1.3057x over previous
//
#include <hip/hip_runtime.h>

// StageBlocks: FPS -> ball-query -> conv/BN/max -> 2x InvResMLP on MI355X.
// Discrete decisions (FPS argmax, ball membership) use contract-off f32 to
// match XLA/np rounding bitwise. BN via sufficient statistics.
// R23 == R21 (best verified: 2466 us). R22's FPS pruning is REVERTED: it
// added ~17 words of live loop state (oid[8], bbox, pkey) and spilled to
// scratch inside the serial loop (VGPR pinned at 88, +940 cyc/iter -- the
// R12 signature). Rule, thrice-confirmed: the FPS loop has zero register
// headroom; any added per-thread state spills.
// Structure: 2-way FPS split (A: m<1024 + conv_x cotenant; B: m>=1024 +
// hidden grid-bq1a), grid ball-query (10^3 pos / 5^3 cent), tail with
// R18-style block-reduced BN stats (256 atomics/block, grp=bid&15).

#define BB 4
#define NN 8192
#define MM 2048
#define HM 1024  // FPS split point
#define KK 32
#define CI 64
#define CO 128
#define SG 16    // stat groups
#define CAPH 192 // grid-bq hit cap (expected 34 bq1 / 69 bq2)

typedef float vf2 __attribute__((ext_vector_type(2)));

// stats layout (doubles)
#define ST_X 0
#define MO_PS 256
#define MO_PE 272
#define ST1 288                     // 2 x SG x 256 (block0, block1)
#define ST2A (288 + 2 * SG * 256)   // 2 x SG x 256
#define ST2B (ST2A + 2 * SG * 256)  // 2 x 256
#define ST_TOTAL (ST2B + 512)

__device__ __forceinline__ float sq3(float dx, float dy, float dz) {
#pragma clang fp contract(off)
  return dx * dx + dy * dy + dz * dz;  // ((x+y)+z), no FMA: matches XLA/np
}

__device__ __forceinline__ void fin_stats_d(const double* st, float gam,
                                            float bet, double cnt, int ch,
                                            float* sc, float* sh) {
  double mean = st[ch] / cnt;
  double var = st[128 + ch] / cnt - mean * mean;
  if (var < 0) var = 0;
  double s = (double)gam / sqrt(var + 1e-5);
  *sc = (float)s;
  *sh = (float)((double)bet - mean * s);
}

// grouped (SG partial sums) variant
__device__ __forceinline__ void fin_grp_d(const double* st, float gam,
                                          float bet, double cnt, int ch,
                                          float* sc, float* sh) {
  double sum = 0, ssq = 0;
#pragma unroll
  for (int g = 0; g < SG; g++) {
    sum += st[g * 256 + ch];
    ssq += st[g * 256 + 128 + ch];
  }
  double mean = sum / cnt;
  double var = ssq / cnt - mean * mean;
  if (var < 0) var = 0;
  double s = (double)gam / sqrt(var + 1e-5);
  *sc = (float)s;
  *sh = (float)((double)bet - mean * s);
}

__device__ __forceinline__ void fin_mom_d(const double* mo, const float* Wrow,
                                          float gam, float bet, double cnt,
                                          float* sc, float* sh) {
  double w0 = Wrow[0], w1 = Wrow[1], w2 = Wrow[2];
  double mx = mo[0] / cnt, my = mo[1] / cnt, mz = mo[2] / cnt;
  double sxx = mo[3] / cnt, sxy = mo[4] / cnt, sxz = mo[5] / cnt;
  double syy = mo[6] / cnt, syz = mo[7] / cnt, szz = mo[8] / cnt;
  double mean = w0 * mx + w1 * my + w2 * mz;
  double ey2 = w0 * w0 * sxx + w1 * w1 * syy + w2 * w2 * szz +
               2.0 * (w0 * w1 * sxy + w0 * w2 * sxz + w1 * w2 * syz);
  double var = ey2 - mean * mean;
  if (var < 0) var = 0;
  double s = (double)gam / sqrt(var + 1e-5);
  *sc = (float)s;
  *sh = (float)((double)bet - mean * s);
}

// ---------------- DPP helpers ----------------
template <int CTRL>
__device__ __forceinline__ int dpp_i(int v) {
  return __builtin_amdgcn_update_dpp(v, v, CTRL, 0xF, 0xF, false);
}
template <int CTRL>
__device__ __forceinline__ float dpp_f(float v) {
  return __int_as_float(dpp_i<CTRL>(__float_as_int(v)));
}

#define FT 512
#define NP 8  // float2 pairs per thread = 16 points
#define NW 8

// ---------------- grid-accelerated ball query (one wave per query) -------
__device__ __forceinline__ void bq_grid(
    int pair, const float* __restrict__ pts, int npts,
    const float4* __restrict__ gxyz, const int* __restrict__ gstart, int G,
    float gs, float rad, float rsq, float inv_r, int* __restrict__ sel,
    const float* __restrict__ cent, int lane, int* __restrict__ s_hitw,
    int* __restrict__ s_selw, float* __restrict__ s_momw) {
  const float* C = cent + (size_t)pair * 3;
  float cx = C[0], cy = C[1], cz = C[2];
  unsigned long long ltm = (1ull << lane) - 1ull;
  int x0 = (int)((cx - rad - 1e-5f) * gs); x0 = x0 < 0 ? 0 : x0;
  int x1 = (int)((cx + rad + 1e-5f) * gs); x1 = x1 > G - 1 ? G - 1 : x1;
  int y0 = (int)((cy - rad - 1e-5f) * gs); y0 = y0 < 0 ? 0 : y0;
  int y1 = (int)((cy + rad + 1e-5f) * gs); y1 = y1 > G - 1 ? G - 1 : y1;
  int z0 = (int)((cz - rad - 1e-5f) * gs); z0 = z0 < 0 ? 0 : z0;
  int z1 = (int)((cz + rad + 1e-5f) * gs); z1 = z1 > G - 1 ? G - 1 : z1;
  int cnt = 0;
  for (int zz = z0; zz <= z1; zz++) {
    for (int yy = y0; yy <= y1; yy++) {
      int brow = (zz * G + yy) * G;
      int sbeg = gstart[brow + x0];
      int send = gstart[brow + x1 + 1];  // x-cells contiguous in bin order
      for (int base = sbeg; base < send; base += 64) {
        int j = base + lane;
        bool h = false;
        int pi = 0;
        if (j < send) {
          float4 v = gxyz[j];
          pi = __float_as_int(v.w);
          h = sq3(v.x - cx, v.y - cy, v.z - cz) < rsq;
        }
        unsigned long long mb = __ballot(h);
        if (mb) {
          int k = cnt + __popcll(mb & ltm);
          if (h && k < CAPH) s_hitw[k] = pi;
          cnt += __popcll(mb);
        }
      }
    }
  }
  __syncthreads();  // collect done, s_hit stable (uniform across waves)
  int total;
  if (cnt <= CAPH) {
    // rank-select: KK smallest indices ascending (indices distinct)
    for (int l = lane; l < cnt; l += 64) {
      int v = s_hitw[l];
      int rk = 0;
      for (int j = 0; j < cnt; j++) rk += (s_hitw[j] < v);
      if (rk < KK) s_selw[rk] = v;
    }
    total = cnt < KK ? cnt : KK;
  } else {
    // brute fallback: index-ordered first-KK scan (never expected)
    int bcnt = 0;
    int nit = npts >> 6;
    for (int ch = 0; ch < nit; ch++) {
      int i0 = (ch << 6) + lane;
      float a0 = pts[i0 * 3 + 0], a1 = pts[i0 * 3 + 1], a2 = pts[i0 * 3 + 2];
      bool h = sq3(a0 - cx, a1 - cy, a2 - cz) < rsq;
      unsigned long long mb = __ballot(h);
      if (mb) {
        int k = bcnt + __popcll(mb & ltm);
        if (h && k < KK) s_selw[k] = i0;
        bcnt += __popcll(mb);
      }
      if (bcnt >= KK) break;
    }
    total = bcnt < KK ? bcnt : KK;
  }
  __syncthreads();  // s_sel stable
  int myidx = 0;
  if (lane < KK) {
    int v = (lane < total) ? s_selw[lane] : s_selw[0];
    sel[(size_t)pair * KK + lane] = v;
    myidx = v;
  }
  float gx = 0.f, gy = 0.f, gz = 0.f;
  if (lane < KK) {
    gx = (pts[myidx * 3 + 0] - cx) * inv_r;
    gy = (pts[myidx * 3 + 1] - cy) * inv_r;
    gz = (pts[myidx * 3 + 2] - cz) * inv_r;
  }
  float v9[9] = {gx, gy, gz, gx * gx, gx * gy, gx * gz, gy * gy, gy * gz,
                 gz * gz};
#pragma unroll
  for (int j = 0; j < 9; j++) {
#pragma unroll
    for (int off = 32; off > 0; off >>= 1) v9[j] += __shfl_xor(v9[j], off);
  }
  if (lane == 0) {
#pragma unroll
    for (int j = 0; j < 9; j++) s_momw[j] = v9[j];
  }
}

// ---- FPS stage A (0..HM) + conv_x cotenant + pos-grid-build cotenant ----
__global__ __launch_bounds__(FT) void k_fps_conv(
    const float* __restrict__ pos, const float* __restrict__ x,
    const float* __restrict__ W_x, float* __restrict__ cent,
    float* __restrict__ fpre, double* __restrict__ stats,
    float* __restrict__ gds, int* __restrict__ pg_start,
    float4* __restrict__ pg_xyz) {
  __shared__ alignas(16) unsigned long long s_key[2][NW];  // 128 B
  __shared__ alignas(16) float s_pts[NN * 3];   // 96 KB point table
  __shared__ alignas(16) float s_cent[MM * 3];  // 24 KB centroid staging
  int t = threadIdx.x;
  if (blockIdx.x >= BB + 256) {
    // ---- pos-grid build: one block per batch (10^3 bins, x-major) ----
    int bb = blockIdx.x - (BB + 256);
    const float* P = pos + (size_t)bb * NN * 3;
    int* cb = (int*)s_pts;  // [1000] counts (alias big LDS)
    int* rb = cb + 1024;    // [1000] running offsets
    for (int i = t; i < 1000; i += FT) cb[i] = 0;
    __syncthreads();
    for (int i = t; i < NN; i += FT) {
      float px = P[i * 3 + 0], py = P[i * 3 + 1], pz = P[i * 3 + 2];
      int bx = (int)(px * 10.f); bx = bx > 9 ? 9 : bx;
      int by = (int)(py * 10.f); by = by > 9 ? 9 : by;
      int bz = (int)(pz * 10.f); bz = bz > 9 ? 9 : bz;
      atomicAdd(&cb[(bz * 10 + by) * 10 + bx], 1);
    }
    __syncthreads();
    if (t == 0) {
      int acc = 0;
      for (int j = 0; j < 1000; j++) {
        pg_start[bb * 1024 + j] = acc;
        rb[j] = acc;
        acc += cb[j];
      }
      pg_start[bb * 1024 + 1000] = acc;  // == NN sentinel
    }
    __syncthreads();
    for (int i = t; i < NN; i += FT) {
      float px = P[i * 3 + 0], py = P[i * 3 + 1], pz = P[i * 3 + 2];
      int bx = (int)(px * 10.f); bx = bx > 9 ? 9 : bx;
      int by = (int)(py * 10.f); by = by > 9 ? 9 : by;
      int bz = (int)(pz * 10.f); bz = bz > 9 ? 9 : bz;
      int slot = atomicAdd(&rb[(bz * 10 + by) * 10 + bx], 1);
      float4 v;
      v.x = px; v.y = py; v.z = pz; v.w = __int_as_float(i);
      pg_xyz[(size_t)bb * NN + slot] = v;
    }
    return;
  }
  if (blockIdx.x >= BB) {
    // ---- conv part: 64->128 over BB*NN rows, 256 blocks x 512 threads ----
    int cb2 = blockIdx.x - BB;
    int o = t & 127, q = t >> 7;  // q wave-uniform
    float4 w[CI / 4];
    const float4* Wv = (const float4*)(W_x + (size_t)o * CI);
#pragma unroll
    for (int i = 0; i < CI / 4; i++) w[i] = Wv[i];
    int row0 = cb2 * 128;
    float ssum = 0.f, ssq = 0.f;
    for (int r = 0; r < 128; r += 4) {
      int row = __builtin_amdgcn_readfirstlane(row0 + r + q);
      const float* xr = x + (size_t)row * CI;
      float acc = 0.f;
#pragma unroll
      for (int i = 0; i < CI / 4; i++) {
        float4 a = *(const float4*)(xr + 4 * i);
        acc += a.x * w[i].x + a.y * w[i].y + a.z * w[i].z + a.w * w[i].w;
      }
      fpre[(size_t)row * CO + o] = acc;
      ssum += acc;
      ssq += acc * acc;
    }
    atomicAdd(&stats[ST_X + o], (double)ssum);
    atomicAdd(&stats[ST_X + 128 + o], (double)ssq);
    return;
  }
  // ---- FPS stage A ----
  int b = blockIdx.x;
  const float* P = pos + (size_t)b * NN * 3;
  float* C = cent + (size_t)b * MM * 3;
  int lane = t & 63, w = t >> 6;
  int ws = __builtin_amdgcn_readfirstlane(w);
  for (int i = t; i < (NN * 3) / 4; i += FT) {
    ((float4*)s_pts)[i] = ((const float4*)P)[i];
  }
  vf2 px[NP], py[NP], pz[NP], ds[NP];
#pragma unroll
  for (int s = 0; s < NP; s++) {
    int ia = (2 * s) * FT + t;
    int ib = ia + FT;
    px[s] = (vf2){P[ia * 3 + 0], P[ib * 3 + 0]};
    py[s] = (vf2){P[ia * 3 + 1], P[ib * 3 + 1]};
    pz[s] = (vf2){P[ia * 3 + 2], P[ib * 3 + 2]};
    ds[s] = (vf2){1e10f, 1e10f};
  }
  float lx = P[0], ly = P[1], lz = P[2];
  if (t == 0) {
    s_cent[0] = lx;
    s_cent[1] = ly;
    s_cent[2] = lz;
  }
  __syncthreads();  // tables ready
  for (int m = 1; m < HM; m++) {
    vf2 l2x = (vf2){lx, lx}, l2y = (vf2){ly, ly}, l2z = (vf2){lz, lz};
    vf2 bmax = (vf2){-1.0f, -1.0f};
    {
#pragma clang fp contract(off)
#pragma unroll
      for (int s = 0; s < NP; s++) {
        vf2 dx = px[s] - l2x;
        vf2 dy = py[s] - l2y;
        vf2 dz = pz[s] - l2z;
        vf2 d2 = dx * dx + dy * dy + dz * dz;  // per-lane IEEE, no FMA
        vf2 nd = __builtin_elementwise_min(ds[s], d2);
        ds[s] = nd;
        bmax = __builtin_elementwise_max(bmax, nd);
      }
    }
    float bv = fmaxf(bmax.x, bmax.y);
    bv = fmaxf(bv, dpp_f<0x111>(bv));
    bv = fmaxf(bv, dpp_f<0x112>(bv));
    bv = fmaxf(bv, dpp_f<0x114>(bv));
    bv = fmaxf(bv, dpp_f<0x118>(bv));
    bv = fmaxf(bv, dpp_f<0x142>(bv));
    bv = fmaxf(bv, dpp_f<0x143>(bv));
    float wmax =
        __int_as_float(__builtin_amdgcn_readlane(__float_as_int(bv), 63));
    unsigned idxw = 0xffffffffu;
#pragma unroll
    for (int s = NP - 1; s >= 0; s--) {
      unsigned long long mby = __ballot(ds[s].y == wmax);
      unsigned basey = (unsigned)((2 * s) * FT + FT + (ws << 6));
      if (mby) idxw = basey + (unsigned)(__ffsll((long long)mby) - 1);
      unsigned long long mbx = __ballot(ds[s].x == wmax);
      unsigned basex = (unsigned)((2 * s) * FT + (ws << 6));
      if (mbx) idxw = basex + (unsigned)(__ffsll((long long)mbx) - 1);
    }
    int pb = m & 1;
    if (lane == 0) {
      s_key[pb][ws] = ((unsigned long long)__float_as_uint(wmax) << 32) |
                      (unsigned long long)(~idxw);
    }
    __syncthreads();  // single barrier per iteration
    const ulonglong2* kp = (const ulonglong2*)(&s_key[pb][0]);
    ulonglong2 q0 = kp[0];
    ulonglong2 q1 = kp[1];
    ulonglong2 q2 = kp[2];
    ulonglong2 q3 = kp[3];
    unsigned long long a0 = q0.x > q0.y ? q0.x : q0.y;
    unsigned long long a1 = q1.x > q1.y ? q1.x : q1.y;
    unsigned long long a2 = q2.x > q2.y ? q2.x : q2.y;
    unsigned long long a3 = q3.x > q3.y ? q3.x : q3.y;
    a0 = a0 > a1 ? a0 : a1;
    a2 = a2 > a3 ? a2 : a3;
    unsigned long long kw = a0 > a2 ? a0 : a2;
    unsigned gidx = ~(unsigned)(kw & 0xffffffffull);
    lx = s_pts[gidx * 3 + 0];
    ly = s_pts[gidx * 3 + 1];
    lz = s_pts[gidx * 3 + 2];
    if (t == 0) {
      s_cent[m * 3 + 0] = lx;
      s_cent[m * 3 + 1] = ly;
      s_cent[m * 3 + 2] = lz;
    }
  }
  __syncthreads();
  // dump centroids 0..HM-1 and ds state (bit-exact carry to stage B)
  for (int i = t; i < (HM * 3) / 4; i += FT) {
    ((float4*)C)[i] = ((const float4*)s_cent)[i];
  }
  float2* gd = (float2*)gds + (size_t)b * NP * FT;
#pragma unroll
  for (int s = 0; s < NP; s++) {
    float2 v;
    v.x = ds[s].x;
    v.y = ds[s].y;
    gd[s * FT + t] = v;
  }
}

// ---------------- FPS stage B (HM..MM) + grid-bq1a cotenant --------------
__global__ __launch_bounds__(FT) void k_fps_bq(
    const float* __restrict__ pos, float* __restrict__ cent,
    const float* __restrict__ gds, int* __restrict__ sel1,
    double* __restrict__ stats, const int* __restrict__ pg_start,
    const float4* __restrict__ pg_xyz) {
  __shared__ alignas(16) unsigned long long s_key[2][NW];
  __shared__ alignas(16) float s_pts[NN * 3];   // 96 KB
  __shared__ alignas(16) float s_cent[MM * 3];  // 24 KB
  __shared__ int s_hit[NW][CAPH];               // 6 KB
  __shared__ int s_sel[NW][KK];
  __shared__ float s_mom[NW][9];
  int t = threadIdx.x;
  int lane = t & 63, w = t >> 6;
  if (blockIdx.x >= BB) {
    // ---- grid-bq1 for first-half centroids (m < HM): 8 pairs/block ----
    int pi = (blockIdx.x - BB) * 8 + w;  // 0..4095
    int bb = pi >> 10, mi = pi & (HM - 1);
    int pair = bb * MM + mi;
    bq_grid(pair, pos + (size_t)bb * NN * 3, NN, pg_xyz + (size_t)bb * NN,
            pg_start + bb * 1024, 10, 10.f, 0.1f, 0.01f, 10.f, sel1, cent,
            lane, s_hit[w], s_sel[w], s_mom[w]);
    __syncthreads();
    if (t < 9) {
      double a = (double)s_mom[0][t];
#pragma unroll
      for (int j = 1; j < NW; j++) a += s_mom[j][t];
      atomicAdd(&stats[MO_PS + t], a);
    }
    return;
  }
  // ---- FPS resume ----
  int b = blockIdx.x;
  const float* P = pos + (size_t)b * NN * 3;
  float* C = cent + (size_t)b * MM * 3;
  int ws = __builtin_amdgcn_readfirstlane(w);
  for (int i = t; i < (NN * 3) / 4; i += FT) {
    ((float4*)s_pts)[i] = ((const float4*)P)[i];
  }
  vf2 px[NP], py[NP], pz[NP], ds[NP];
  const float2* gd = (const float2*)gds + (size_t)b * NP * FT;
#pragma unroll
  for (int s = 0; s < NP; s++) {
    int ia = (2 * s) * FT + t;
    int ib = ia + FT;
    px[s] = (vf2){P[ia * 3 + 0], P[ib * 3 + 0]};
    py[s] = (vf2){P[ia * 3 + 1], P[ib * 3 + 1]};
    pz[s] = (vf2){P[ia * 3 + 2], P[ib * 3 + 2]};
    float2 v = gd[s * FT + t];
    ds[s] = (vf2){v.x, v.y};
  }
  float lx = C[(HM - 1) * 3 + 0];
  float ly = C[(HM - 1) * 3 + 1];
  float lz = C[(HM - 1) * 3 + 2];
  __syncthreads();  // tables ready
  for (int m = HM; m < MM; m++) {
    vf2 l2x = (vf2){lx, lx}, l2y = (vf2){ly, ly}, l2z = (vf2){lz, lz};
    vf2 bmax = (vf2){-1.0f, -1.0f};
    {
#pragma clang fp contract(off)
#pragma unroll
      for (int s = 0; s < NP; s++) {
        vf2 dx = px[s] - l2x;
        vf2 dy = py[s] - l2y;
        vf2 dz = pz[s] - l2z;
        vf2 d2 = dx * dx + dy * dy + dz * dz;  // per-lane IEEE, no FMA
        vf2 nd = __builtin_elementwise_min(ds[s], d2);
        ds[s] = nd;
        bmax = __builtin_elementwise_max(bmax, nd);
      }
    }
    float bv = fmaxf(bmax.x, bmax.y);
    bv = fmaxf(bv, dpp_f<0x111>(bv));
    bv = fmaxf(bv, dpp_f<0x112>(bv));
    bv = fmaxf(bv, dpp_f<0x114>(bv));
    bv = fmaxf(bv, dpp_f<0x118>(bv));
    bv = fmaxf(bv, dpp_f<0x142>(bv));
    bv = fmaxf(bv, dpp_f<0x143>(bv));
    float wmax =
        __int_as_float(__builtin_amdgcn_readlane(__float_as_int(bv), 63));
    unsigned idxw = 0xffffffffu;
#pragma unroll
    for (int s = NP - 1; s >= 0; s--) {
      unsigned long long mby = __ballot(ds[s].y == wmax);
      unsigned basey = (unsigned)((2 * s) * FT + FT + (ws << 6));
      if (mby) idxw = basey + (unsigned)(__ffsll((long long)mby) - 1);
      unsigned long long mbx = __ballot(ds[s].x == wmax);
      unsigned basex = (unsigned)((2 * s) * FT + (ws << 6));
      if (mbx) idxw = basex + (unsigned)(__ffsll((long long)mbx) - 1);
    }
    int pb = m & 1;
    if (lane == 0) {
      s_key[pb][ws] = ((unsigned long long)__float_as_uint(wmax) << 32) |
                      (unsigned long long)(~idxw);
    }
    __syncthreads();
    const ulonglong2* kp = (const ulonglong2*)(&s_key[pb][0]);
    ulonglong2 q0 = kp[0];
    ulonglong2 q1 = kp[1];
    ulonglong2 q2 = kp[2];
    ulonglong2 q3 = kp[3];
    unsigned long long a0 = q0.x > q0.y ? q0.x : q0.y;
    unsigned long long a1 = q1.x > q1.y ? q1.x : q1.y;
    unsigned long long a2 = q2.x > q2.y ? q2.x : q2.y;
    unsigned long long a3 = q3.x > q3.y ? q3.x : q3.y;
    a0 = a0 > a1 ? a0 : a1;
    a2 = a2 > a3 ? a2 : a3;
    unsigned long long kw = a0 > a2 ? a0 : a2;
    unsigned gidx = ~(unsigned)(kw & 0xffffffffull);
    lx = s_pts[gidx * 3 + 0];
    ly = s_pts[gidx * 3 + 1];
    lz = s_pts[gidx * 3 + 2];
    if (t == 0) {
      s_cent[m * 3 + 0] = lx;
      s_cent[m * 3 + 1] = ly;
      s_cent[m * 3 + 2] = lz;
    }
  }
  __syncthreads();
  for (int i = t + (HM * 3) / 4; i < (MM * 3) / 4; i += FT) {
    ((float4*)C)[i] = ((const float4*)s_cent)[i];
  }
}

// ---------------- cent-grid build (5^3 bins, one block per batch) --------
__global__ __launch_bounds__(256) void k_bin_cent(const float* __restrict__ cent,
                                                  int* __restrict__ cg_start,
                                                  float4* __restrict__ cg_xyz) {
  __shared__ int cb[128], rb[128];
  int t = threadIdx.x, bb = blockIdx.x;
  const float* C = cent + (size_t)bb * MM * 3;
  for (int i = t; i < 125; i += 256) cb[i] = 0;
  __syncthreads();
  for (int i = t; i < MM; i += 256) {
    float px = C[i * 3 + 0], py = C[i * 3 + 1], pz = C[i * 3 + 2];
    int bx = (int)(px * 5.f); bx = bx > 4 ? 4 : bx;
    int by = (int)(py * 5.f); by = by > 4 ? 4 : by;
    int bz = (int)(pz * 5.f); bz = bz > 4 ? 4 : bz;
    atomicAdd(&cb[(bz * 5 + by) * 5 + bx], 1);
  }
  __syncthreads();
  if (t == 0) {
    int acc = 0;
    for (int j = 0; j < 125; j++) {
      cg_start[bb * 128 + j] = acc;
      rb[j] = acc;
      acc += cb[j];
    }
    cg_start[bb * 128 + 125] = acc;  // == MM sentinel
  }
  __syncthreads();
  for (int i = t; i < MM; i += 256) {
    float px = C[i * 3 + 0], py = C[i * 3 + 1], pz = C[i * 3 + 2];
    int bx = (int)(px * 5.f); bx = bx > 4 ? 4 : bx;
    int by = (int)(py * 5.f); by = by > 4 ? 4 : by;
    int bz = (int)(pz * 5.f); bz = bz > 4 ? 4 : bz;
    int slot = atomicAdd(&rb[(bz * 5 + by) * 5 + bx], 1);
    float4 v;
    v.x = px; v.y = py; v.z = pz; v.w = __int_as_float(i);
    cg_xyz[(size_t)bb * MM + slot] = v;
  }
}

// ---------------- grid-bq: visible bq1 [HM,MM) + bq2 (all) ---------------
__global__ __launch_bounds__(256) void k_bq_rest(
    const float* __restrict__ pos, const float* __restrict__ cent,
    const int* __restrict__ pg_start, const float4* __restrict__ pg_xyz,
    const int* __restrict__ cg_start, const float4* __restrict__ cg_xyz,
    int* __restrict__ sel1, int* __restrict__ sel2,
    double* __restrict__ stats) {
  __shared__ int s_hit[4][CAPH];
  __shared__ int s_sel[4][KK];
  __shared__ float s_mom[4][9];
  int t = threadIdx.x, lane = t & 63, w = t >> 6;
  int mo;
  if (blockIdx.x < (BB * (MM - HM)) / 4) {  // 1024 blocks: bq1 m >= HM
    int pi = blockIdx.x * 4 + w;            // 0..4095
    int bb = pi >> 10;                      // MM-HM == 1024
    int mi = (pi & (HM - 1)) + HM;
    int pair = bb * MM + mi;
    bq_grid(pair, pos + (size_t)bb * NN * 3, NN, pg_xyz + (size_t)bb * NN,
            pg_start + bb * 1024, 10, 10.f, 0.1f, 0.01f, 10.f, sel1, cent,
            lane, s_hit[w], s_sel[w], s_mom[w]);
    mo = MO_PS;
  } else {  // 2048 blocks: bq2, all pairs
    int pi = (blockIdx.x - (BB * (MM - HM)) / 4) * 4 + w;  // 0..8191
    int bb = pi >> 11;
    bq_grid(pi, cent + (size_t)bb * MM * 3, MM, cg_xyz + (size_t)bb * MM,
            cg_start + bb * 128, 5, 5.f, 0.2f, 0.04f, 5.f, sel2, cent, lane,
            s_hit[w], s_sel[w], s_mom[w]);
    mo = MO_PE;
  }
  __syncthreads();
  if (t < 9) {
    double a = (double)s_mom[0][t] + s_mom[1][t] + s_mom[2][t] + s_mom[3][t];
    atomicAdd(&stats[mo + t], a);
  }
}

// ------ fused stage-1 aggregation + conv1(block0): 32 pairs/block --------
__global__ __launch_bounds__(512) void k_xf_conv1(
    const float* __restrict__ pos, const float* __restrict__ cent,
    const int* __restrict__ sel1, const float* __restrict__ fpre,
    const float* __restrict__ Wps, const float* __restrict__ g_ps,
    const float* __restrict__ b_ps, const float* __restrict__ g_x,
    const float* __restrict__ b_x, const double* __restrict__ stats,
    const float* __restrict__ W1, float* __restrict__ y1a,
    double* __restrict__ st1out) {
  __shared__ alignas(16) float s_sx[128], s_hx[128], s_sp[128], s_hp[128];
  __shared__ alignas(16) float s_w0[128], s_w1[128], s_w2[128];
  __shared__ alignas(16) int s_idx[4][KK];
  __shared__ alignas(16) float s_xf[4][128];
  __shared__ alignas(16) double s_rs[4][128], s_rq[4][128];
  int t = threadIdx.x, bid = blockIdx.x;
  if (t < 128) {
    float sx, hx, sp, hp;
    fin_stats_d(stats + ST_X, g_x[t], b_x[t], (double)(BB * NN), t, &sx, &hx);
    fin_mom_d(stats + MO_PS, Wps + t * 3, g_ps[t], b_ps[t],
              (double)(BB * MM * KK), &sp, &hp);
    s_sx[t] = sx;
    s_hx[t] = hx;
    s_sp[t] = sp;
    s_hp[t] = hp;
    s_w0[t] = Wps[t * 3 + 0];
    s_w1[t] = Wps[t * 3 + 1];
    s_w2[t] = Wps[t * 3 + 2];
  }
  __syncthreads();
  int o = t & 127, sub = t >> 7;  // sub 0..3, wave-uniform
  float sx = s_sx[o], hx = s_hx[o], sp = s_sp[o], hp = s_hp[o];
  float w0 = s_w0[o], w1 = s_w1[o], w2 = s_w2[o];
  double rsum = 0.0, rsq = 0.0;
  for (int p = 0; p < 8; p++) {
    int pair = bid * 32 + p * 4 + sub;
    int b = pair >> 11;
    const float* C = cent + (size_t)pair * 3;
    float cx = C[0], cy = C[1], cz = C[2];
    const float* P = pos + (size_t)b * NN * 3;
    const float* F = fpre + (size_t)b * NN * CO;
    if (o < KK) s_idx[sub][o] = sel1[(size_t)pair * KK + o];
    __syncthreads();
    float acc = -1e30f;
#pragma unroll 4
    for (int k = 0; k < KK; k++) {
      int idx = __builtin_amdgcn_readfirstlane(s_idx[sub][k]);
      float gx = (P[idx * 3 + 0] - cx) * 10.0f;
      float gy = (P[idx * 3 + 1] - cy) * 10.0f;
      float gz = (P[idx * 3 + 2] - cz) * 10.0f;
      float y = fmaxf((w0 * gx + w1 * gy + w2 * gz) * sp + hp, 0.f);
      float f = fmaxf(F[(size_t)idx * CO + o] * sx + hx, 0.f);
      float v = y + f;
      acc = v > acc ? v : acc;
    }
    s_xf[sub][o] = acc;
    __syncthreads();
    const float4* Wv = (const float4*)(W1 + (size_t)o * CO);
    const float4* gv = (const float4*)(&s_xf[sub][0]);
    float dot = 0.f;
#pragma unroll
    for (int i = 0; i < CO / 4; i++) {
      float4 a = gv[i];
      float4 ww = Wv[i];
      dot += a.x * ww.x + a.y * ww.y + a.z * ww.z + a.w * ww.w;
    }
    y1a[(size_t)pair * CO + o] = dot;
    rsum += (double)dot;
    rsq += (double)(dot * dot);
  }
  s_rs[sub][o] = rsum;
  s_rq[sub][o] = rsq;
  __syncthreads();
  int grp = bid & (SG - 1);
  if (t < 128) {
    double a = s_rs[0][t] + s_rs[1][t] + s_rs[2][t] + s_rs[3][t];
    atomicAdd(&st1out[grp * 256 + t], a);
  } else if (t < 256) {
    int c = t - 128;
    double a = s_rq[0][c] + s_rq[1][c] + s_rq[2][c] + s_rq[3][c];
    atomicAdd(&st1out[grp * 256 + 128 + c], a);
  }
}

// ---------------- conv with relu(bn(in)) input, scales from grouped stats -
__global__ __launch_bounds__(256) void k_conv_bnin(
    const float* __restrict__ in, const float* __restrict__ W,
    const double* __restrict__ st_grp, const float* __restrict__ gam,
    const float* __restrict__ bet, float* __restrict__ out,
    double* __restrict__ stats, int rows_per_block) {
  __shared__ float s_sc[128], s_sh[128];
  int t = threadIdx.x;
  if (t < 128) {
    fin_grp_d(st_grp, gam[t], bet[t], (double)(BB * MM), t, &s_sc[t],
              &s_sh[t]);
  }
  __syncthreads();
  int o = t & 127, half = t >> 7;
  float4 w[CO / 4];
  const float4* Wv = (const float4*)(W + (size_t)o * CO);
#pragma unroll
  for (int i = 0; i < CO / 4; i++) w[i] = Wv[i];
  int row0 = blockIdx.x * rows_per_block;
  float ssum = 0.f, ssq = 0.f;
  for (int r = 0; r < rows_per_block; r += 2) {
    int row = __builtin_amdgcn_readfirstlane(row0 + r + half);
    const float* xr = in + (size_t)row * CO;
    float acc = 0.f;
#pragma unroll
    for (int i = 0; i < CO / 4; i++) {
      float4 a = *(const float4*)(xr + 4 * i);
      a.x = fmaxf(a.x * s_sc[4 * i + 0] + s_sh[4 * i + 0], 0.f);
      a.y = fmaxf(a.y * s_sc[4 * i + 1] + s_sh[4 * i + 1], 0.f);
      a.z = fmaxf(a.z * s_sc[4 * i + 2] + s_sh[4 * i + 2], 0.f);
      a.w = fmaxf(a.w * s_sc[4 * i + 3] + s_sh[4 * i + 3], 0.f);
      acc += a.x * w[i].x + a.y * w[i].y + a.z * w[i].z + a.w * w[i].w;
    }
    out[(size_t)row * CO + o] = acc;
    ssum += acc;
    ssq += acc * acc;
  }
  atomicAdd(&stats[o], (double)ssum);
  atomicAdd(&stats[128 + o], (double)ssq);
}

// ---------------- conv1 of block 1 with resid-of-block-0 fused input -----
__global__ __launch_bounds__(256) void k_conv_resid(
    const float* __restrict__ y1prev, const float* __restrict__ y2bprev,
    const double* __restrict__ st1p, const float* __restrict__ g1p,
    const float* __restrict__ b1p, const double* __restrict__ st2bp,
    const float* __restrict__ g2bp, const float* __restrict__ b2bp,
    const float* __restrict__ W, float* __restrict__ y1out,
    double* __restrict__ stats, int rows_per_block) {
  __shared__ float s_s1[128], s_h1[128], s_s2[128], s_h2[128];
  int t = threadIdx.x;
  if (t < 128) {
    fin_grp_d(st1p, g1p[t], b1p[t], (double)(BB * MM), t, &s_s1[t], &s_h1[t]);
    fin_stats_d(st2bp, g2bp[t], b2bp[t], (double)(BB * MM), t, &s_s2[t],
                &s_h2[t]);
  }
  __syncthreads();
  int o = t & 127, half = t >> 7;
  float4 w[CO / 4];
  const float4* Wv = (const float4*)(W + (size_t)o * CO);
#pragma unroll
  for (int i = 0; i < CO / 4; i++) w[i] = Wv[i];
  int row0 = blockIdx.x * rows_per_block;
  float ssum = 0.f, ssq = 0.f;
  for (int r = 0; r < rows_per_block; r += 2) {
    int row = __builtin_amdgcn_readfirstlane(row0 + r + half);
    const float* ar = y1prev + (size_t)row * CO;
    const float* br = y2bprev + (size_t)row * CO;
    float acc = 0.f;
#pragma unroll
    for (int i = 0; i < CO / 4; i++) {
      float4 a = *(const float4*)(ar + 4 * i);
      float4 bb = *(const float4*)(br + 4 * i);
      float x0 = fmaxf(fmaxf(a.x * s_s1[4 * i + 0] + s_h1[4 * i + 0], 0.f) +
                           (bb.x * s_s2[4 * i + 0] + s_h2[4 * i + 0]), 0.f);
      float x1 = fmaxf(fmaxf(a.y * s_s1[4 * i + 1] + s_h1[4 * i + 1], 0.f) +
                           (bb.y * s_s2[4 * i + 1] + s_h2[4 * i + 1]), 0.f);
      float x2 = fmaxf(fmaxf(a.z * s_s1[4 * i + 2] + s_h1[4 * i + 2], 0.f) +
                           (bb.z * s_s2[4 * i + 2] + s_h2[4 * i + 2]), 0.f);
      float x3 = fmaxf(fmaxf(a.w * s_s1[4 * i + 3] + s_h1[4 * i + 3], 0.f) +
                           (bb.w * s_s2[4 * i + 3] + s_h2[4 * i + 3]), 0.f);
      acc += x0 * w[i].x + x1 * w[i].y + x2 * w[i].z + x3 * w[i].w;
    }
    y1out[(size_t)row * CO + o] = acc;
    ssum += acc;
    ssq += acc * acc;
  }
  int grp = blockIdx.x & (SG - 1);
  atomicAdd(&stats[grp * 256 + o], (double)ssum);
  atomicAdd(&stats[grp * 256 + 128 + o], (double)ssq);
}

// ------ fused: g = max_k(relu(bn1(y1[sel2])) + pe); y2a = W2a*g ----------
__global__ __launch_bounds__(512) void k_gconv(
    const float* __restrict__ cent, const int* __restrict__ sel2,
    const float* __restrict__ y1in, const double* __restrict__ st1,
    const float* __restrict__ g1v, const float* __restrict__ b1v,
    const double* __restrict__ mo_pe, const float* __restrict__ Wpe,
    const float* __restrict__ gpe, const float* __restrict__ bpe,
    const float* __restrict__ W2a, float* __restrict__ y2a,
    double* __restrict__ st2a) {
  __shared__ alignas(16) float s_s1[128], s_h1[128], s_se[128], s_he[128];
  __shared__ alignas(16) float s_w0[128], s_w1[128], s_w2[128];
  __shared__ alignas(16) int s_idx[4][KK];
  __shared__ alignas(16) float s_g[4][128];
  __shared__ alignas(16) double s_rs[4][128], s_rq[4][128];
  int t = threadIdx.x, bid = blockIdx.x;
  if (t < 128) {
    float s1, h1, se, he;
    fin_grp_d(st1, g1v[t], b1v[t], (double)(BB * MM), t, &s1, &h1);
    fin_mom_d(mo_pe, Wpe + t * 3, gpe[t], bpe[t], (double)(BB * MM * KK), &se,
              &he);
    s_s1[t] = s1;
    s_h1[t] = h1;
    s_se[t] = se;
    s_he[t] = he;
    s_w0[t] = Wpe[t * 3 + 0];
    s_w1[t] = Wpe[t * 3 + 1];
    s_w2[t] = Wpe[t * 3 + 2];
  }
  __syncthreads();
  int o = t & 127, sub = t >> 7;  // sub 0..3, wave-uniform
  float s1 = s_s1[o], h1 = s_h1[o], se = s_se[o], he = s_he[o];
  float w0 = s_w0[o], w1 = s_w1[o], w2 = s_w2[o];
  double rsum = 0.0, rsq = 0.0;
  for (int p = 0; p < 8; p++) {
    int pair = bid * 32 + p * 4 + sub;
    int b = pair >> 11;
    const float* C = cent + (size_t)pair * 3;
    float cx = C[0], cy = C[1], cz = C[2];
    const float* CB = cent + (size_t)b * MM * 3;
    const float* Y = y1in + (size_t)b * MM * CO;
    if (o < KK) s_idx[sub][o] = sel2[(size_t)pair * KK + o];
    __syncthreads();
    float acc = -1e30f;
#pragma unroll 4
    for (int k = 0; k < KK; k++) {
      int idx = __builtin_amdgcn_readfirstlane(s_idx[sub][k]);
      float gx = (CB[idx * 3 + 0] - cx) * 5.0f;
      float gy = (CB[idx * 3 + 1] - cy) * 5.0f;
      float gz = (CB[idx * 3 + 2] - cz) * 5.0f;
      float pe = fmaxf((w0 * gx + w1 * gy + w2 * gz) * se + he, 0.f);
      float f = fmaxf(Y[(size_t)idx * CO + o] * s1 + h1, 0.f);
      float v = pe + f;
      acc = v > acc ? v : acc;
    }
    s_g[sub][o] = acc;
    __syncthreads();
    const float4* Wv = (const float4*)(W2a + (size_t)o * CO);
    const float4* gv = (const float4*)(&s_g[sub][0]);
    float dot = 0.f;
#pragma unroll
    for (int i = 0; i < CO / 4; i++) {
      float4 a = gv[i];
      float4 ww = Wv[i];
      dot += a.x * ww.x + a.y * ww.y + a.z * ww.z + a.w * ww.w;
    }
    y2a[(size_t)pair * CO + o] = dot;
    rsum += (double)dot;
    rsq += (double)(dot * dot);
  }
  s_rs[sub][o] = rsum;
  s_rq[sub][o] = rsq;
  __syncthreads();
  int grp = bid & (SG - 1);
  if (t < 128) {
    double a = s_rs[0][t] + s_rs[1][t] + s_rs[2][t] + s_rs[3][t];
    atomicAdd(&st2a[grp * 256 + t], a);
  } else if (t < 256) {
    int c = t - 128;
    double a = s_rq[0][c] + s_rq[1][c] + s_rq[2][c] + s_rq[3][c];
    atomicAdd(&st2a[grp * 256 + 128 + c], a);
  }
}

// ---------------- final residual (fin folded per-thread) ----------------
__global__ __launch_bounds__(256) void k_resid_fin(
    const float* __restrict__ y1b, const double* __restrict__ st1,
    const float* __restrict__ g1v, const float* __restrict__ b1v,
    const float* __restrict__ y2b, const double* __restrict__ st2b,
    const float* __restrict__ g2bv, const float* __restrict__ b2bv,
    float* __restrict__ xf) {
  int i = blockIdx.x * 256 + threadIdx.x;
  int o = i & 127;
  float s1, h1, s2, h2;
  fin_grp_d(st1, g1v[o], b1v[o], (double)(BB * MM), o, &s1, &h1);
  fin_stats_d(st2b, g2bv[o], b2bv[o], (double)(BB * MM), o, &s2, &h2);
  float f = fmaxf(y1b[i] * s1 + h1, 0.f);
  float v = y2b[i] * s2 + h2;
  xf[i] = fmaxf(f + v, 0.f);
}

extern "C" void kernel_launch(void* const* d_in, const int* in_sizes, int n_in,
                              void* d_out, int out_size, void* d_ws,
                              size_t ws_size, hipStream_t stream) {
  const float* pos = (const float*)d_in[0];
  const float* x = (const float*)d_in[1];
  const float* W_x = (const float*)d_in[2];
  const float* g_x = (const float*)d_in[3];
  const float* b_x = (const float*)d_in[4];
  const float* W_ps = (const float*)d_in[5];
  const float* g_ps = (const float*)d_in[6];
  const float* b_ps = (const float*)d_in[7];
  const float* W_pe = (const float*)d_in[8];
  const float* g_pe = (const float*)d_in[9];
  const float* b_pe = (const float*)d_in[10];
  const float* W1 = (const float*)d_in[11];
  const float* g1 = (const float*)d_in[12];
  const float* b1 = (const float*)d_in[13];
  const float* W2a = (const float*)d_in[14];
  const float* g2a = (const float*)d_in[15];
  const float* b2a = (const float*)d_in[16];
  const float* W2b = (const float*)d_in[17];
  const float* g2b = (const float*)d_in[18];
  const float* b2b = (const float*)d_in[19];

  float* cent = (float*)d_out;             // (B,M,3)
  float* xf = cent + (size_t)BB * MM * 3;  // (B,M,128)

  char* p = (char*)d_ws;
  double* stats = (double*)p; p += (size_t)ST_TOTAL * sizeof(double);
  int* sel1 = (int*)p;        p += (size_t)BB * MM * KK * sizeof(int);
  int* sel2 = (int*)p;        p += (size_t)BB * MM * KK * sizeof(int);
  float* fpre = (float*)p;    p += (size_t)BB * NN * CO * sizeof(float);
  float* y1a = (float*)p;     p += (size_t)BB * MM * CO * sizeof(float);
  float* y1b = (float*)p;     p += (size_t)BB * MM * CO * sizeof(float);
  float* y2a = (float*)p;     p += (size_t)BB * MM * CO * sizeof(float);
  float* y2b = (float*)p;     p += (size_t)BB * MM * CO * sizeof(float);
  float* gds = (float*)p;     p += (size_t)BB * NP * FT * 2 * sizeof(float);
  float4* pg_xyz = (float4*)p; p += (size_t)BB * NN * sizeof(float4);
  float4* cg_xyz = (float4*)p; p += (size_t)BB * MM * sizeof(float4);
  int* pg_start = (int*)p;    p += (size_t)BB * 1024 * sizeof(int);
  int* cg_start = (int*)p;    p += (size_t)BB * 128 * sizeof(int);

  hipMemsetAsync(stats, 0, (size_t)ST_TOTAL * sizeof(double), stream);
  k_fps_conv<<<BB + 256 + BB, FT, 0, stream>>>(pos, x, W_x, cent, fpre, stats,
                                               gds, pg_start, pg_xyz);
  k_fps_bq<<<BB + (BB * HM) / 8, FT, 0, stream>>>(pos, cent, gds, sel1, stats,
                                                  pg_start, pg_xyz);
  k_bin_cent<<<BB, 256, 0, stream>>>(cent, cg_start, cg_xyz);
  k_bq_rest<<<(BB * (MM - HM)) / 4 + (BB * MM) / 4, 256, 0, stream>>>(
      pos, cent, pg_start, pg_xyz, cg_start, cg_xyz, sel1, sel2, stats);
  k_xf_conv1<<<256, 512, 0, stream>>>(pos, cent, sel1, fpre, W_ps, g_ps,
                                      b_ps, g_x, b_x, stats, W1, y1a,
                                      stats + ST1);
  // ---- InvResMLP block 0 ----
  k_gconv<<<256, 512, 0, stream>>>(cent, sel2, y1a, stats + ST1, g1, b1,
                                   stats + MO_PE, W_pe, g_pe, b_pe, W2a, y2a,
                                   stats + ST2A);
  k_conv_bnin<<<128, 256, 0, stream>>>(y2a, W2b, stats + ST2A, g2a, b2a, y2b,
                                       stats + ST2B, 64);
  // ---- InvResMLP block 1 (resid of block 0 fused into conv1) ----
  k_conv_resid<<<128, 256, 0, stream>>>(
      y1a, y2b, stats + ST1, g1, b1, stats + ST2B, g2b, b2b, W1 + CO * CO, y1b,
      stats + ST1 + SG * 256, 64);
  k_gconv<<<256, 512, 0, stream>>>(cent, sel2, y1b, stats + ST1 + SG * 256,
                                   g1 + 128, b1 + 128, stats + MO_PE, W_pe,
                                   g_pe, b_pe, W2a + CO * CO, y2a,
                                   stats + ST2A + SG * 256);
  k_conv_bnin<<<128, 256, 0, stream>>>(y2a, W2b + CO * CO,
                                       stats + ST2A + SG * 256, g2a + 128,
                                       b2a + 128, y2b, stats + ST2B + 256, 64);
  k_resid_fin<<<(BB * MM * CO) / 256, 256, 0, stream>>>(
      y1b, stats + ST1 + SG * 256, g1 + 128, b1 + 128, y2b,
      stats + ST2B + 256, g2b + 128, b2b + 128, xf);
}